// Round 16
// baseline (190.799 us; speedup 1.0000x reference)
//
#include <hip/hip_runtime.h>
#include <math.h>

// CSWin3DBlock: B=4, T=8, RES=32, C=128. fp32 I/O; f16 MFMA internals.
// GEMMs: LDS-staged row-major f16 weights, 512-thread blocks (8 waves:
// 4 m-tiles x 2 N-halves).  QKV window-major: [br][head][win][512][16] f16.
// k_attn: query-split 2 blocks per (br,win,head) -> 1024 blocks.
namespace {
constexpr int C_ = 128;
constexpr int BL = 32768;

typedef __attribute__((ext_vector_type(4))) float f32x4;
typedef __attribute__((ext_vector_type(4))) _Float16 f16x4;
typedef __attribute__((ext_vector_type(8))) _Float16 f16x8;
typedef __attribute__((ext_vector_type(2))) __fp16 hf2;

#if __has_builtin(__builtin_amdgcn_exp2f)
#define EXP2F(x) __builtin_amdgcn_exp2f(x)
#else
#define EXP2F(x) exp2f(x)
#endif
} // namespace

// ---------------------------------------------------------------------------
// Kernel 0: weights fp32 -> f16 row-major (Q rows pre-scaled by 0.25*log2e),
// plus LePE conv-weight transpose to [2][27][64].
// ---------------------------------------------------------------------------
__global__ __launch_bounds__(256) void k_cvt(
    const float* __restrict__ qkvw, const float* __restrict__ pw,
    const float* __restrict__ f1w,  const float* __restrict__ f2w,
    const float* __restrict__ cw0,  const float* __restrict__ cw1,
    _Float16* __restrict__ wqh, _Float16* __restrict__ pwh,
    _Float16* __restrict__ w1h, _Float16* __restrict__ w2h,
    float* __restrict__ lepw)
{
  int i = blockIdx.x * 256 + threadIdx.x;
  if (i < 49152) {
    float v = qkvw[i];
    if (i < 16384) v *= 0.360673762f;    // Q rows: fold 0.25*log2(e)
    wqh[i] = (_Float16)v;
  }
  else if (i < 65536)  pwh[i - 49152] = (_Float16)pw[i - 49152];
  else if (i < 131072) w1h[i - 65536] = (_Float16)f1w[i - 65536];
  else if (i < 196608) w2h[i - 131072] = (_Float16)f2w[i - 131072];
  else if (i < 200064) {
    int j = i - 196608;
    int br = j / 1728, r = j % 1728, widx = r >> 6, ch = r & 63;
    lepw[j] = (br ? cw1 : cw0)[ch * 27 + widx];
  }
}

// ---------------------------------------------------------------------------
// Kernel 1: LayerNorm1 + QKV GEMM + windowed scatter.
// 64 tokens/block, 512 threads (8 waves: mq x4, nh x2).  (R15, passing)
// ---------------------------------------------------------------------------
__global__ __launch_bounds__(512) void k_ln_qkv(
    const float* __restrict__ x,
    const float* __restrict__ nw,
    const float* __restrict__ nb,
    const _Float16* __restrict__ wqh,
    _Float16* __restrict__ qh, _Float16* __restrict__ kh, _Float16* __restrict__ vh)
{
  __shared__ _Float16 xs[64][136];     // 17408 B
  __shared__ _Float16 qt[64][136];     // 17408 B
  __shared__ _Float16 wbuf[128][136];  // 34816 B  (total 69632)
  const int tid = threadIdx.x;
  const int row0 = blockIdx.x << 6;
  const int bb = row0 >> 13, t = (row0 >> 10) & 7, h0 = (row0 >> 5) & 31;
  const int tb = t >> 2, t_in = t & 3;

  {
    const int r = tid >> 3, j = tid & 7;
    const float* xp = x + (size_t)(row0 + r) * C_ + j * 16;
    float v[16];
#pragma unroll
    for (int i = 0; i < 4; ++i) {
      float4 u = ((const float4*)xp)[i];
      v[i*4+0] = u.x; v[i*4+1] = u.y; v[i*4+2] = u.z; v[i*4+3] = u.w;
    }
    float s1 = 0.f, s2 = 0.f;
#pragma unroll
    for (int i = 0; i < 16; ++i) { s1 += v[i]; s2 += v[i] * v[i]; }
    s1 += __shfl_down(s1, 4, 8); s1 += __shfl_down(s1, 2, 8); s1 += __shfl_down(s1, 1, 8);
    s2 += __shfl_down(s2, 4, 8); s2 += __shfl_down(s2, 2, 8); s2 += __shfl_down(s2, 1, 8);
    float mu = __shfl(s1, 0, 8) * (1.f / 128.f);
    float ms = __shfl(s2, 0, 8) * (1.f / 128.f);
    float rstd = rsqrtf(ms - mu * mu + 1e-5f);
#pragma unroll
    for (int i = 0; i < 16; ++i) {
      int c = j * 16 + i;
      xs[r][c] = (_Float16)((v[i] - mu) * rstd * nw[c] + nb[c]);
    }
  }
  __syncthreads();

  const int lane = tid & 63, wave = tid >> 6;   // 8 waves
  const int mq = wave & 3, nh = wave >> 2;
  const int m0 = mq << 4, mi = lane & 15, quad = lane >> 4;

  f16x8 afr[4];
#pragma unroll
  for (int kt = 0; kt < 4; ++kt)
    afr[kt] = *(const f16x8*)&xs[m0 + mi][kt * 32 + quad * 8];

  for (int g = 0; g < 3; ++g) {
#pragma unroll
    for (int it = 0; it < 4; ++it) {
      int id = it * 512 + tid;           // 2048 units
      int r = id >> 4, c8 = id & 15;
      *(uint4*)&wbuf[r][c8 * 8] = *(const uint4*)(wqh + (size_t)(g * 128 + r) * 128 + c8 * 8);
    }
    __syncthreads();

    f32x4 acc[4];
#pragma unroll
    for (int nt = 0; nt < 4; ++nt) acc[nt] = (f32x4){0.f, 0.f, 0.f, 0.f};
#pragma unroll
    for (int nt = 0; nt < 4; ++nt) {
      int wrow = (nh * 4 + nt) * 16 + mi;
#pragma unroll
      for (int kt = 0; kt < 4; ++kt) {
        f16x8 bfr = *(const f16x8*)&wbuf[wrow][kt * 32 + quad * 8];
        acc[nt] = __builtin_amdgcn_mfma_f32_16x16x32_f16(afr[kt], bfr, acc[nt], 0, 0, 0);
      }
    }
#pragma unroll
    for (int nt = 0; nt < 4; ++nt) {
      int n = (nh * 4 + nt) * 16 + mi;
#pragma unroll
      for (int rr = 0; rr < 4; ++rr)
        qt[m0 + quad * 4 + rr][n] = (_Float16)acc[nt][rr];
    }
    __syncthreads();

    _Float16* G = (g == 0) ? qh : (g == 1) ? kh : vh;
#pragma unroll
    for (int it = 0; it < 2; ++it) {
      int u = it * 512 + tid;            // 1024 units of 16 B
      if (u < 512) {                     // branch 0: Hsp=32, Wsp=4
        int half = u & 1, p = (u >> 1) & 7, head = (u >> 4) & 3, sb = u >> 6;
        int token = (p >> 2) * 32 + sb * 4 + (p & 3);
        uint4 d = *(const uint4*)&qt[token][head * 16 + half * 8];
        int win = bb * 16 + tb * 8 + sb;
        int pos = t_in * 128 + h0 * 4 + p;
        *(uint4*)(G + ((size_t)(head * 64 + win) * 512 + pos) * 16 + half * 8) = d;
      } else {                           // branch 1: Hsp=4, Wsp=32
        int u2 = u - 512;
        int half = u2 & 1, pin = (u2 >> 1) & 63, head = u2 >> 7;
        uint4 d = *(const uint4*)&qt[pin][64 + head * 16 + half * 8];
        int win = bb * 16 + tb * 8 + (h0 >> 2);
        int pos = t_in * 128 + (h0 & 3) * 32 + pin;
        *(uint4*)(G + ((size_t)((4 + head) * 64 + win) * 512 + pos) * 16 + half * 8) = d;
      }
    }
    __syncthreads();
  }
}

// ---------------------------------------------------------------------------
// Kernel 2: MFMA flash attention + LePE.  Query-split: 1024 blocks x 512
// threads; each block = (br, win, head, query-half).  Full K/V staged,
// 2 qi chains per wave.
// ---------------------------------------------------------------------------
__global__ __launch_bounds__(512) void k_attn(
    const _Float16* __restrict__ qh,
    const _Float16* __restrict__ kh,
    const _Float16* __restrict__ vh,
    const float* __restrict__ lepw,
    const float* __restrict__ cb0,
    const float* __restrict__ cb1,
    _Float16* __restrict__ attnh)
{
  __shared__ _Float16 Ks[512][20];
  __shared__ _Float16 Vs[512][20];

  const int tid = threadIdx.x;
  const int bid = blockIdx.x;
  const int br = bid >> 9, wi = (bid >> 3) & 63, head = (bid >> 1) & 3, qs = bid & 1;
  const int b = wi >> 4, tb = (wi >> 3) & 1, sb = wi & 7;
  const int coff = br * 64 + head * 16;
  const int Hsp = br ? 4 : 32, Wsp = br ? 32 : 4;
  const float* cb = br ? cb1 : cb0;
  const size_t base = ((size_t)(br * 4 + head) * 64 + wi) * 512 * 16;

  auto token_of = [&](int p) -> int {
    int t_in = p >> 7;
    int rem = p & 127;
    int h, w;
    if (br == 0) { h = rem >> 2;            w = sb * 4 + (rem & 3); }
    else         { h = sb * 4 + (rem >> 5); w = rem & 31; }
    return ((b * 8 + tb * 4 + t_in) << 10) + (h << 5) + w;
  };

  {
    const int r = tid;
    const _Float16* kp = kh + base + r * 16;
    const _Float16* vp = vh + base + r * 16;
    f16x8 k0 = *(const f16x8*)kp;
    f16x8 k1 = *(const f16x8*)(kp + 8);
    f16x8 v0 = *(const f16x8*)vp;
    f16x8 v1 = *(const f16x8*)(vp + 8);
    *(f16x4*)&Ks[r][0]  = (f16x4){k0[0], k0[1], k0[2], k0[3]};
    *(f16x4*)&Ks[r][4]  = (f16x4){k0[4], k0[5], k0[6], k0[7]};
    *(f16x4*)&Ks[r][8]  = (f16x4){k1[0], k1[1], k1[2], k1[3]};
    *(f16x4*)&Ks[r][12] = (f16x4){k1[4], k1[5], k1[6], k1[7]};
    *(f16x4*)&Vs[r][0]  = (f16x4){v0[0], v0[1], v0[2], v0[3]};
    *(f16x4*)&Vs[r][4]  = (f16x4){v0[4], v0[5], v0[6], v0[7]};
    *(f16x4*)&Vs[r][8]  = (f16x4){v1[0], v1[1], v1[2], v1[3]};
    *(f16x4*)&Vs[r][12] = (f16x4){v1[4], v1[5], v1[6], v1[7]};
  }

  const int lane = tid & 63, wave = tid >> 6;   // 8 waves
  const int mi = lane & 15, quad = lane >> 4;

  int qtok[2];
  f16x4 qfr[2];
#pragma unroll
  for (int qi = 0; qi < 2; ++qi) {
    int q = qs * 256 + (wave * 2 + qi) * 16 + mi;
    qtok[qi] = token_of(q);
    qfr[qi] = *(const f16x4*)(qh + base + q * 16 + quad * 4);
  }
  __syncthreads();

  f32x4 acc[2];
  float l[2];
#pragma unroll
  for (int qi = 0; qi < 2; ++qi) { acc[qi] = (f32x4){0.f,0.f,0.f,0.f}; l[qi] = 0.f; }

  const hf2 one2 = {(__fp16)1.f, (__fp16)1.f};

  for (int kt = 0; kt < 32; ++kt) {
    const int kb = kt << 4;
    f16x4 kfr = *(const f16x4*)&Ks[kb + mi][quad * 4];
    f16x4 vfr;
    vfr[0] = Vs[kb + quad * 4 + 0][mi];
    vfr[1] = Vs[kb + quad * 4 + 1][mi];
    vfr[2] = Vs[kb + quad * 4 + 2][mi];
    vfr[3] = Vs[kb + quad * 4 + 3][mi];
#pragma unroll
    for (int qi = 0; qi < 2; ++qi) {
      f32x4 s = __builtin_amdgcn_mfma_f32_16x16x16f16(kfr, qfr[qi], (f32x4){0.f,0.f,0.f,0.f}, 0, 0, 0);
      float p0 = EXP2F(s[0]);
      float p1 = EXP2F(s[1]);
      float p2 = EXP2F(s[2]);
      float p3 = EXP2F(s[3]);
      hf2 plo = __builtin_amdgcn_cvt_pkrtz(p0, p1);
      hf2 phi = __builtin_amdgcn_cvt_pkrtz(p2, p3);
#if __has_builtin(__builtin_amdgcn_fdot2)
      l[qi] = __builtin_amdgcn_fdot2(plo, one2, l[qi], false);
      l[qi] = __builtin_amdgcn_fdot2(phi, one2, l[qi], false);
#else
      l[qi] += (p0 + p1) + (p2 + p3);
#endif
      union { struct { hf2 lo, hi; } h; f16x4 v; } u;
      u.h.lo = plo; u.h.hi = phi;
      acc[qi] = __builtin_amdgcn_mfma_f32_16x16x16f16(vfr, u.v, acc[qi], 0, 0, 0);
    }
  }

#pragma unroll
  for (int qi = 0; qi < 2; ++qi) {
    float lq = l[qi];
    lq += __shfl_xor(lq, 16, 64);
    lq += __shfl_xor(lq, 32, 64);
    float inv = 1.f / lq;

    const int q = qs * 256 + (wave * 2 + qi) * 16 + mi;
    int t_in = q >> 7, rem = q & 127;
    int h_in, w_in;
    if (br == 0) { h_in = rem >> 2; w_in = rem & 3; }
    else         { h_in = rem >> 5; w_in = rem & 31; }
    float4 lep = *(const float4*)(cb + head * 16 + quad * 4);
    for (int dz = 0; dz < 3; ++dz) {
      int tz = t_in + dz - 1; if ((unsigned)tz >= 4u) continue;
      for (int dy = 0; dy < 3; ++dy) {
        int ty = h_in + dy - 1; if ((unsigned)ty >= (unsigned)Hsp) continue;
        for (int dx = 0; dx < 3; ++dx) {
          int tx = w_in + dx - 1; if ((unsigned)tx >= (unsigned)Wsp) continue;
          int np = (tz * Hsp + ty) * Wsp + tx;
          int widx = (dz * 3 + dy) * 3 + dx;
          float4 w4 = *(const float4*)(lepw + ((br * 27 + widx) << 6) + head * 16 + quad * 4);
          f16x4 vv = *(const f16x4*)&Vs[np][quad * 4];
          lep.x += w4.x * (float)vv[0];
          lep.y += w4.y * (float)vv[1];
          lep.z += w4.z * (float)vv[2];
          lep.w += w4.w * (float)vv[3];
        }
      }
    }
    f16x4 ov;
    ov[0] = (_Float16)(acc[qi][0] * inv + lep.x);
    ov[1] = (_Float16)(acc[qi][1] * inv + lep.y);
    ov[2] = (_Float16)(acc[qi][2] * inv + lep.z);
    ov[3] = (_Float16)(acc[qi][3] * inv + lep.w);
    *(f16x4*)(attnh + (size_t)qtok[qi] * 128 + coff + quad * 4) = ov;
  }
}

// ---------------------------------------------------------------------------
// Kernel 3: proj GEMM + bias + residual -> xrh f16.
// 64 tokens/block, 512 threads (8 waves: mq x4, nh x2).  (R15, passing)
// ---------------------------------------------------------------------------
__global__ __launch_bounds__(512) void k_proj(
    const _Float16* __restrict__ attnh,
    const _Float16* __restrict__ pwh,
    const float* __restrict__ pb,
    const float* __restrict__ x,
    _Float16* __restrict__ xrh)
{
  __shared__ _Float16 as_[64][136];     // 17408 B
  __shared__ _Float16 wbuf[128][136];   // 34816 B  (52224)
  const int tid = threadIdx.x;
  const int row0 = blockIdx.x << 6;

#pragma unroll
  for (int it = 0; it < 2; ++it) {
    int id = it * 512 + tid;             // 1024 units
    int r = id >> 4, c8 = id & 15;
    *(uint4*)&as_[r][c8 * 8] = *(const uint4*)(attnh + (size_t)(row0 + r) * 128 + c8 * 8);
  }
#pragma unroll
  for (int it = 0; it < 4; ++it) {
    int id = it * 512 + tid;             // 2048 units
    int r = id >> 4, c8 = id & 15;
    *(uint4*)&wbuf[r][c8 * 8] = *(const uint4*)(pwh + (size_t)r * 128 + c8 * 8);
  }
  __syncthreads();

  const int lane = tid & 63, wave = tid >> 6;
  const int mq = wave & 3, nh = wave >> 2;
  const int m0 = mq << 4, mi = lane & 15, quad = lane >> 4;

  f16x8 afr[4];
#pragma unroll
  for (int kt = 0; kt < 4; ++kt)
    afr[kt] = *(const f16x8*)&as_[m0 + mi][kt * 32 + quad * 8];

  f32x4 acc[4];
#pragma unroll
  for (int nt = 0; nt < 4; ++nt) acc[nt] = (f32x4){0.f, 0.f, 0.f, 0.f};
#pragma unroll
  for (int nt = 0; nt < 4; ++nt) {
    int wrow = (nh * 4 + nt) * 16 + mi;
#pragma unroll
    for (int kt = 0; kt < 4; ++kt) {
      f16x8 bfr = *(const f16x8*)&wbuf[wrow][kt * 32 + quad * 8];
      acc[nt] = __builtin_amdgcn_mfma_f32_16x16x32_f16(afr[kt], bfr, acc[nt], 0, 0, 0);
    }
  }
  __syncthreads();   // all as_ reads done before rewrite
#pragma unroll
  for (int nt = 0; nt < 4; ++nt) {
    int n = (nh * 4 + nt) * 16 + mi;
    float bb = pb[n];
#pragma unroll
    for (int rr = 0; rr < 4; ++rr)
      as_[m0 + quad * 4 + rr][n] = (_Float16)(acc[nt][rr] + bb);
  }
  __syncthreads();

#pragma unroll
  for (int it = 0; it < 2; ++it) {
    int id = it * 512 + tid;
    int r = id >> 4, c8 = id & 15;
    f16x8 v = *(const f16x8*)&as_[r][c8 * 8];
    const float* xp = x + (size_t)(row0 + r) * 128 + c8 * 8;
    float4 xa = *(const float4*)xp;
    float4 xb = *(const float4*)(xp + 4);
    f16x8 o;
    o[0] = (_Float16)((float)v[0] + xa.x); o[1] = (_Float16)((float)v[1] + xa.y);
    o[2] = (_Float16)((float)v[2] + xa.z); o[3] = (_Float16)((float)v[3] + xa.w);
    o[4] = (_Float16)((float)v[4] + xb.x); o[5] = (_Float16)((float)v[5] + xb.y);
    o[6] = (_Float16)((float)v[6] + xb.z); o[7] = (_Float16)((float)v[7] + xb.w);
    *(f16x8*)(xrh + (size_t)(row0 + r) * 128 + c8 * 8) = o;
  }
}

// ---------------------------------------------------------------------------
// Kernel 4: LayerNorm2 + fc1 + GELU + fc2 + residual.  (R14, passing)
// 64 tokens/block, 512 threads = 8 waves (mt x4, hh x2).
// ---------------------------------------------------------------------------
__global__ __launch_bounds__(512) void k_mlp(
    const _Float16* __restrict__ xrh,
    const float* __restrict__ nw,
    const float* __restrict__ nb,
    const _Float16* __restrict__ w1h,
    const float* __restrict__ f1b,
    const _Float16* __restrict__ w2h,
    const float* __restrict__ f2b,
    float* __restrict__ out)
{
  __shared__ _Float16 xs[64][136];      // 17408 B
  __shared__ _Float16 wbuf[128][136];   // 34816 B (also reduce buffer)
  const int tid = threadIdx.x;
  const int row0 = blockIdx.x << 6;

  {
    const int r = tid >> 3, j = tid & 7;
    const _Float16* xp = xrh + (size_t)(row0 + r) * C_ + j * 16;
    float v[16];
#pragma unroll
    for (int i = 0; i < 2; ++i) {
      f16x8 u = ((const f16x8*)xp)[i];
#pragma unroll
      for (int k = 0; k < 8; ++k) v[i * 8 + k] = (float)u[k];
    }
    float s1 = 0.f, s2 = 0.f;
#pragma unroll
    for (int i = 0; i < 16; ++i) { s1 += v[i]; s2 += v[i] * v[i]; }
    s1 += __shfl_down(s1, 4, 8); s1 += __shfl_down(s1, 2, 8); s1 += __shfl_down(s1, 1, 8);
    s2 += __shfl_down(s2, 4, 8); s2 += __shfl_down(s2, 2, 8); s2 += __shfl_down(s2, 1, 8);
    float mu = __shfl(s1, 0, 8) * (1.f / 128.f);
    float ms = __shfl(s2, 0, 8) * (1.f / 128.f);
    float rstd = rsqrtf(ms - mu * mu + 1e-5f);
#pragma unroll
    for (int i = 0; i < 16; ++i) {
      int c = j * 16 + i;
      xs[r][c] = (_Float16)((v[i] - mu) * rstd * nw[c] + nb[c]);
    }
  }
  __syncthreads();

  const int lane = tid & 63, wave = tid >> 6;   // 8 waves
  const int mt = wave & 3, hh = wave >> 2;
  const int tok0 = mt << 4, mi = lane & 15, quad = lane >> 4;

  f16x8 bx[4];
#pragma unroll
  for (int kt = 0; kt < 4; ++kt)
    bx[kt] = *(const f16x8*)&xs[tok0 + mi][kt * 32 + quad * 8];

  f32x4 oacc[8];
#pragma unroll
  for (int o = 0; o < 8; ++o) oacc[o] = (f32x4){0.f, 0.f, 0.f, 0.f};

  for (int ng = 0; ng < 4; ++ng) {
#pragma unroll
    for (int it = 0; it < 4; ++it) {
      int id = it * 512 + tid;
      int r = id >> 4, c8 = id & 15;
      *(uint4*)&wbuf[r][c8 * 8] = *(const uint4*)(w1h + (size_t)(ng * 128 + r) * 128 + c8 * 8);
    }
    __syncthreads();

    f32x4 hacc[4];
#pragma unroll
    for (int t = 0; t < 4; ++t) hacc[t] = (f32x4){0.f, 0.f, 0.f, 0.f};
#pragma unroll
    for (int t = 0; t < 4; ++t) {
      int hrow = hh * 64 + t * 16 + mi;
#pragma unroll
      for (int kt = 0; kt < 4; ++kt) {
        f16x8 wfr = *(const f16x8*)&wbuf[hrow][kt * 32 + quad * 8];
        hacc[t] = __builtin_amdgcn_mfma_f32_16x16x32_f16(wfr, bx[kt], hacc[t], 0, 0, 0);
      }
    }
    f16x4 ph[4];
#pragma unroll
    for (int t = 0; t < 4; ++t) {
      float4 bj = *(const float4*)(f1b + ng * 128 + hh * 64 + t * 16 + quad * 4);
      float h0v = hacc[t][0] + bj.x;
      float h1v = hacc[t][1] + bj.y;
      float h2v = hacc[t][2] + bj.z;
      float h3v = hacc[t][3] + bj.w;
      ph[t][0] = (_Float16)(0.5f * h0v * (1.f + erff(h0v * 0.70710678118654752f)));
      ph[t][1] = (_Float16)(0.5f * h1v * (1.f + erff(h1v * 0.70710678118654752f)));
      ph[t][2] = (_Float16)(0.5f * h2v * (1.f + erff(h2v * 0.70710678118654752f)));
      ph[t][3] = (_Float16)(0.5f * h3v * (1.f + erff(h3v * 0.70710678118654752f)));
    }
    __syncthreads();

#pragma unroll
    for (int it = 0; it < 4; ++it) {
      int id = it * 512 + tid;
      int r = id >> 4, c8 = id & 15;
      *(uint4*)&wbuf[r][c8 * 8] = *(const uint4*)(w2h + (size_t)r * 512 + ng * 128 + c8 * 8);
    }
    __syncthreads();

#pragma unroll
    for (int o = 0; o < 8; ++o) {
#pragma unroll
      for (int t = 0; t < 4; ++t) {
        f16x4 wfr = *(const f16x4*)&wbuf[o * 16 + mi][(hh * 4 + t) * 16 + quad * 4];
        oacc[o] = __builtin_amdgcn_mfma_f32_16x16x16f16(wfr, ph[t], oacc[o], 0, 0, 0);
      }
    }
    __syncthreads();
  }

  float* rbuf = (float*)wbuf;   // 32 * 256 * 4 = 32768 B
  if (hh == 1) {
#pragma unroll
    for (int o = 0; o < 8; ++o)
#pragma unroll
      for (int k = 0; k < 4; ++k)
        rbuf[(o * 4 + k) * 256 + mt * 64 + lane] = oacc[o][k];
  }
  __syncthreads();
  if (hh == 0) {
#pragma unroll
    for (int o = 0; o < 8; ++o)
#pragma unroll
      for (int k = 0; k < 4; ++k)
        oacc[o][k] += rbuf[(o * 4 + k) * 256 + mt * 64 + lane];

#pragma unroll
    for (int o = 0; o < 8; ++o) {
      int row = row0 + tok0 + mi;
      int cb4 = o * 16 + quad * 4;
      float4 bo = *(const float4*)(f2b + cb4);
      f16x4 res = *(const f16x4*)(xrh + (size_t)row * C_ + cb4);
      float4 ov;
      ov.x = oacc[o][0] + bo.x + (float)res[0];
      ov.y = oacc[o][1] + bo.y + (float)res[1];
      ov.z = oacc[o][2] + bo.z + (float)res[2];
      ov.w = oacc[o][3] + bo.w + (float)res[3];
      *(float4*)(out + (size_t)row * C_ + cb4) = ov;
    }
  }
}

// ---------------------------------------------------------------------------
extern "C" void kernel_launch(void* const* d_in, const int* in_sizes, int n_in,
                              void* d_out, int out_size, void* d_ws, size_t ws_size,
                              hipStream_t stream)
{
  const float* x    = (const float*)d_in[0];
  const float* n1w  = (const float*)d_in[1];
  const float* n1b  = (const float*)d_in[2];
  const float* qkvw = (const float*)d_in[3];
  const float* cw0  = (const float*)d_in[4];
  const float* cb0  = (const float*)d_in[5];
  const float* cw1  = (const float*)d_in[6];
  const float* cb1  = (const float*)d_in[7];
  const float* pw   = (const float*)d_in[8];
  const float* pb   = (const float*)d_in[9];
  const float* n2w  = (const float*)d_in[10];
  const float* n2b  = (const float*)d_in[11];
  const float* f1w  = (const float*)d_in[12];
  const float* f1b  = (const float*)d_in[13];
  const float* f2w  = (const float*)d_in[14];
  const float* f2b  = (const float*)d_in[15];

  char* ws = (char*)d_ws;
  _Float16* qh    = (_Float16*)ws;                    //  8388608 B
  _Float16* kh    = (_Float16*)(ws +  8388608);       //  8388608 B
  _Float16* vh    = (_Float16*)(ws + 16777216);       //  8388608 B
  _Float16* attnh = (_Float16*)(ws + 25165824);       //  8388608 B
  _Float16* xrh   = (_Float16*)(ws + 33554432);       //  8388608 B
  _Float16* wqh   = (_Float16*)(ws + 41943040);       //    98304 B
  _Float16* pwh   = (_Float16*)(ws + 42041344);       //    32768 B
  _Float16* w1h   = (_Float16*)(ws + 42074112);       //   131072 B
  _Float16* w2h   = (_Float16*)(ws + 42205184);       //   131072 B
  float*    lepw  = (float*)   (ws + 42336256);       //    13824 B

  k_cvt   <<<782,      256, 0, stream>>>(qkvw, pw, f1w, f2w, cw0, cw1,
                                         wqh, pwh, w1h, w2h, lepw);
  k_ln_qkv<<<BL / 64,  512, 0, stream>>>(x, n1w, n1b, wqh, qh, kh, vh);
  k_attn  <<<1024,     512, 0, stream>>>(qh, kh, vh, lepw, cb0, cb1, attnh);
  k_proj  <<<BL / 64,  512, 0, stream>>>(attnh, pwh, pb, x, xrh);
  k_mlp   <<<BL / 64,  512, 0, stream>>>(xrh, n2w, n2b, w1h, f1b, w2h, f2b,
                                         (float*)d_out);
}

// Round 17
// 185.248 us; speedup vs baseline: 1.0300x; 1.0300x over previous
//
#include <hip/hip_runtime.h>
#include <math.h>

// CSWin3DBlock: B=4, T=8, RES=32, C=128. fp32 I/O; f16 MFMA internals.
// LDS stride 140 (280 B == 6 banks mod 32): <=2-way conflicts on b128
// fragment reads (stride 136 gave 8-way).  Sigmoid-GELU in k_mlp.
namespace {
constexpr int C_ = 128;
constexpr int BL = 32768;
constexpr int LS = 140;          // LDS row stride (f16 elems)

typedef __attribute__((ext_vector_type(4))) float f32x4;
typedef __attribute__((ext_vector_type(4))) _Float16 f16x4;
typedef __attribute__((ext_vector_type(8))) _Float16 f16x8;
typedef __attribute__((ext_vector_type(2))) __fp16 hf2;

#if __has_builtin(__builtin_amdgcn_exp2f)
#define EXP2F(x) __builtin_amdgcn_exp2f(x)
#else
#define EXP2F(x) exp2f(x)
#endif
} // namespace

// ---------------------------------------------------------------------------
// Kernel 0: weights fp32 -> f16 row-major (Q rows pre-scaled by 0.25*log2e),
// plus LePE conv-weight transpose to [2][27][64].
// ---------------------------------------------------------------------------
__global__ __launch_bounds__(256) void k_cvt(
    const float* __restrict__ qkvw, const float* __restrict__ pw,
    const float* __restrict__ f1w,  const float* __restrict__ f2w,
    const float* __restrict__ cw0,  const float* __restrict__ cw1,
    _Float16* __restrict__ wqh, _Float16* __restrict__ pwh,
    _Float16* __restrict__ w1h, _Float16* __restrict__ w2h,
    float* __restrict__ lepw)
{
  int i = blockIdx.x * 256 + threadIdx.x;
  if (i < 49152) {
    float v = qkvw[i];
    if (i < 16384) v *= 0.360673762f;    // Q rows: fold 0.25*log2(e)
    wqh[i] = (_Float16)v;
  }
  else if (i < 65536)  pwh[i - 49152] = (_Float16)pw[i - 49152];
  else if (i < 131072) w1h[i - 65536] = (_Float16)f1w[i - 65536];
  else if (i < 196608) w2h[i - 131072] = (_Float16)f2w[i - 131072];
  else if (i < 200064) {
    int j = i - 196608;
    int br = j / 1728, r = j % 1728, widx = r >> 6, ch = r & 63;
    lepw[j] = (br ? cw1 : cw0)[ch * 27 + widx];
  }
}

// ---------------------------------------------------------------------------
// Kernel 1: LayerNorm1 + QKV GEMM + windowed scatter.
// 64 tokens/block, 512 threads (8 waves: mq x4, nh x2).
// ---------------------------------------------------------------------------
__global__ __launch_bounds__(512) void k_ln_qkv(
    const float* __restrict__ x,
    const float* __restrict__ nw,
    const float* __restrict__ nb,
    const _Float16* __restrict__ wqh,
    _Float16* __restrict__ qh, _Float16* __restrict__ kh, _Float16* __restrict__ vh)
{
  __shared__ _Float16 xs[64][LS];      // 17920 B
  __shared__ _Float16 qt[64][LS];      // 17920 B
  __shared__ _Float16 wbuf[128][LS];   // 35840 B  (total 71680)
  const int tid = threadIdx.x;
  const int row0 = blockIdx.x << 6;
  const int bb = row0 >> 13, t = (row0 >> 10) & 7, h0 = (row0 >> 5) & 31;
  const int tb = t >> 2, t_in = t & 3;

  {
    const int r = tid >> 3, j = tid & 7;
    const float* xp = x + (size_t)(row0 + r) * C_ + j * 16;
    float v[16];
#pragma unroll
    for (int i = 0; i < 4; ++i) {
      float4 u = ((const float4*)xp)[i];
      v[i*4+0] = u.x; v[i*4+1] = u.y; v[i*4+2] = u.z; v[i*4+3] = u.w;
    }
    float s1 = 0.f, s2 = 0.f;
#pragma unroll
    for (int i = 0; i < 16; ++i) { s1 += v[i]; s2 += v[i] * v[i]; }
    s1 += __shfl_down(s1, 4, 8); s1 += __shfl_down(s1, 2, 8); s1 += __shfl_down(s1, 1, 8);
    s2 += __shfl_down(s2, 4, 8); s2 += __shfl_down(s2, 2, 8); s2 += __shfl_down(s2, 1, 8);
    float mu = __shfl(s1, 0, 8) * (1.f / 128.f);
    float ms = __shfl(s2, 0, 8) * (1.f / 128.f);
    float rstd = rsqrtf(ms - mu * mu + 1e-5f);
#pragma unroll
    for (int i = 0; i < 16; ++i) {
      int c = j * 16 + i;
      xs[r][c] = (_Float16)((v[i] - mu) * rstd * nw[c] + nb[c]);
    }
  }
  __syncthreads();

  const int lane = tid & 63, wave = tid >> 6;   // 8 waves
  const int mq = wave & 3, nh = wave >> 2;
  const int m0 = mq << 4, mi = lane & 15, quad = lane >> 4;

  f16x8 afr[4];
#pragma unroll
  for (int kt = 0; kt < 4; ++kt)
    afr[kt] = *(const f16x8*)&xs[m0 + mi][kt * 32 + quad * 8];

  for (int g = 0; g < 3; ++g) {
#pragma unroll
    for (int it = 0; it < 4; ++it) {
      int id = it * 512 + tid;           // 2048 units
      int r = id >> 4, c8 = id & 15;
      *(uint4*)&wbuf[r][c8 * 8] = *(const uint4*)(wqh + (size_t)(g * 128 + r) * 128 + c8 * 8);
    }
    __syncthreads();

    f32x4 acc[4];
#pragma unroll
    for (int nt = 0; nt < 4; ++nt) acc[nt] = (f32x4){0.f, 0.f, 0.f, 0.f};
#pragma unroll
    for (int nt = 0; nt < 4; ++nt) {
      int wrow = (nh * 4 + nt) * 16 + mi;
#pragma unroll
      for (int kt = 0; kt < 4; ++kt) {
        f16x8 bfr = *(const f16x8*)&wbuf[wrow][kt * 32 + quad * 8];
        acc[nt] = __builtin_amdgcn_mfma_f32_16x16x32_f16(afr[kt], bfr, acc[nt], 0, 0, 0);
      }
    }
#pragma unroll
    for (int nt = 0; nt < 4; ++nt) {
      int n = (nh * 4 + nt) * 16 + mi;
#pragma unroll
      for (int rr = 0; rr < 4; ++rr)
        qt[m0 + quad * 4 + rr][n] = (_Float16)acc[nt][rr];
    }
    __syncthreads();

    _Float16* G = (g == 0) ? qh : (g == 1) ? kh : vh;
#pragma unroll
    for (int it = 0; it < 2; ++it) {
      int u = it * 512 + tid;            // 1024 units of 16 B
      if (u < 512) {                     // branch 0: Hsp=32, Wsp=4
        int half = u & 1, p = (u >> 1) & 7, head = (u >> 4) & 3, sb = u >> 6;
        int token = (p >> 2) * 32 + sb * 4 + (p & 3);
        uint4 d = *(const uint4*)&qt[token][head * 16 + half * 8];
        int win = bb * 16 + tb * 8 + sb;
        int pos = t_in * 128 + h0 * 4 + p;
        *(uint4*)(G + ((size_t)(head * 64 + win) * 512 + pos) * 16 + half * 8) = d;
      } else {                           // branch 1: Hsp=4, Wsp=32
        int u2 = u - 512;
        int half = u2 & 1, pin = (u2 >> 1) & 63, head = u2 >> 7;
        uint4 d = *(const uint4*)&qt[pin][64 + head * 16 + half * 8];
        int win = bb * 16 + tb * 8 + (h0 >> 2);
        int pos = t_in * 128 + (h0 & 3) * 32 + pin;
        *(uint4*)(G + ((size_t)((4 + head) * 64 + win) * 512 + pos) * 16 + half * 8) = d;
      }
    }
    __syncthreads();
  }
}

// ---------------------------------------------------------------------------
// Kernel 2: MFMA flash attention + LePE.  Query-split: 1024 blocks x 512
// threads; qs in the HIGH bid bit so block pairs sharing K/V map to the
// same XCD (bid and bid+512 are congruent mod 8).
// ---------------------------------------------------------------------------
__global__ __launch_bounds__(512) void k_attn(
    const _Float16* __restrict__ qh,
    const _Float16* __restrict__ kh,
    const _Float16* __restrict__ vh,
    const float* __restrict__ lepw,
    const float* __restrict__ cb0,
    const float* __restrict__ cb1,
    _Float16* __restrict__ attnh)
{
  __shared__ _Float16 Ks[512][20];
  __shared__ _Float16 Vs[512][20];

  const int tid = threadIdx.x;
  const int bid = blockIdx.x;
  const int qs = bid >> 9, rest = bid & 511;
  const int br = rest >> 8, wi = (rest >> 2) & 63, head = rest & 3;
  const int b = wi >> 4, tb = (wi >> 3) & 1, sb = wi & 7;
  const int coff = br * 64 + head * 16;
  const int Hsp = br ? 4 : 32, Wsp = br ? 32 : 4;
  const float* cb = br ? cb1 : cb0;
  const size_t base = ((size_t)(br * 4 + head) * 64 + wi) * 512 * 16;

  auto token_of = [&](int p) -> int {
    int t_in = p >> 7;
    int rem = p & 127;
    int h, w;
    if (br == 0) { h = rem >> 2;            w = sb * 4 + (rem & 3); }
    else         { h = sb * 4 + (rem >> 5); w = rem & 31; }
    return ((b * 8 + tb * 4 + t_in) << 10) + (h << 5) + w;
  };

  {
    const int r = tid;
    const _Float16* kp = kh + base + r * 16;
    const _Float16* vp = vh + base + r * 16;
    f16x8 k0 = *(const f16x8*)kp;
    f16x8 k1 = *(const f16x8*)(kp + 8);
    f16x8 v0 = *(const f16x8*)vp;
    f16x8 v1 = *(const f16x8*)(vp + 8);
    *(f16x4*)&Ks[r][0]  = (f16x4){k0[0], k0[1], k0[2], k0[3]};
    *(f16x4*)&Ks[r][4]  = (f16x4){k0[4], k0[5], k0[6], k0[7]};
    *(f16x4*)&Ks[r][8]  = (f16x4){k1[0], k1[1], k1[2], k1[3]};
    *(f16x4*)&Ks[r][12] = (f16x4){k1[4], k1[5], k1[6], k1[7]};
    *(f16x4*)&Vs[r][0]  = (f16x4){v0[0], v0[1], v0[2], v0[3]};
    *(f16x4*)&Vs[r][4]  = (f16x4){v0[4], v0[5], v0[6], v0[7]};
    *(f16x4*)&Vs[r][8]  = (f16x4){v1[0], v1[1], v1[2], v1[3]};
    *(f16x4*)&Vs[r][12] = (f16x4){v1[4], v1[5], v1[6], v1[7]};
  }

  const int lane = tid & 63, wave = tid >> 6;   // 8 waves
  const int mi = lane & 15, quad = lane >> 4;

  int qtok[2];
  f16x4 qfr[2];
#pragma unroll
  for (int qi = 0; qi < 2; ++qi) {
    int q = qs * 256 + (wave * 2 + qi) * 16 + mi;
    qtok[qi] = token_of(q);
    qfr[qi] = *(const f16x4*)(qh + base + q * 16 + quad * 4);
  }
  __syncthreads();

  f32x4 acc[2];
  float l[2];
#pragma unroll
  for (int qi = 0; qi < 2; ++qi) { acc[qi] = (f32x4){0.f,0.f,0.f,0.f}; l[qi] = 0.f; }

  const hf2 one2 = {(__fp16)1.f, (__fp16)1.f};

  for (int kt = 0; kt < 32; ++kt) {
    const int kb = kt << 4;
    f16x4 kfr = *(const f16x4*)&Ks[kb + mi][quad * 4];
    f16x4 vfr;
    vfr[0] = Vs[kb + quad * 4 + 0][mi];
    vfr[1] = Vs[kb + quad * 4 + 1][mi];
    vfr[2] = Vs[kb + quad * 4 + 2][mi];
    vfr[3] = Vs[kb + quad * 4 + 3][mi];
#pragma unroll
    for (int qi = 0; qi < 2; ++qi) {
      f32x4 s = __builtin_amdgcn_mfma_f32_16x16x16f16(kfr, qfr[qi], (f32x4){0.f,0.f,0.f,0.f}, 0, 0, 0);
      float p0 = EXP2F(s[0]);
      float p1 = EXP2F(s[1]);
      float p2 = EXP2F(s[2]);
      float p3 = EXP2F(s[3]);
      hf2 plo = __builtin_amdgcn_cvt_pkrtz(p0, p1);
      hf2 phi = __builtin_amdgcn_cvt_pkrtz(p2, p3);
#if __has_builtin(__builtin_amdgcn_fdot2)
      l[qi] = __builtin_amdgcn_fdot2(plo, one2, l[qi], false);
      l[qi] = __builtin_amdgcn_fdot2(phi, one2, l[qi], false);
#else
      l[qi] += (p0 + p1) + (p2 + p3);
#endif
      union { struct { hf2 lo, hi; } h; f16x4 v; } u;
      u.h.lo = plo; u.h.hi = phi;
      acc[qi] = __builtin_amdgcn_mfma_f32_16x16x16f16(vfr, u.v, acc[qi], 0, 0, 0);
    }
  }

#pragma unroll
  for (int qi = 0; qi < 2; ++qi) {
    float lq = l[qi];
    lq += __shfl_xor(lq, 16, 64);
    lq += __shfl_xor(lq, 32, 64);
    float inv = 1.f / lq;

    const int q = qs * 256 + (wave * 2 + qi) * 16 + mi;
    int t_in = q >> 7, rem = q & 127;
    int h_in, w_in;
    if (br == 0) { h_in = rem >> 2; w_in = rem & 3; }
    else         { h_in = rem >> 5; w_in = rem & 31; }
    float4 lep = *(const float4*)(cb + head * 16 + quad * 4);
    for (int dz = 0; dz < 3; ++dz) {
      int tz = t_in + dz - 1; if ((unsigned)tz >= 4u) continue;
      for (int dy = 0; dy < 3; ++dy) {
        int ty = h_in + dy - 1; if ((unsigned)ty >= (unsigned)Hsp) continue;
        for (int dx = 0; dx < 3; ++dx) {
          int tx = w_in + dx - 1; if ((unsigned)tx >= (unsigned)Wsp) continue;
          int np = (tz * Hsp + ty) * Wsp + tx;
          int widx = (dz * 3 + dy) * 3 + dx;
          float4 w4 = *(const float4*)(lepw + ((br * 27 + widx) << 6) + head * 16 + quad * 4);
          f16x4 vv = *(const f16x4*)&Vs[np][quad * 4];
          lep.x += w4.x * (float)vv[0];
          lep.y += w4.y * (float)vv[1];
          lep.z += w4.z * (float)vv[2];
          lep.w += w4.w * (float)vv[3];
        }
      }
    }
    f16x4 ov;
    ov[0] = (_Float16)(acc[qi][0] * inv + lep.x);
    ov[1] = (_Float16)(acc[qi][1] * inv + lep.y);
    ov[2] = (_Float16)(acc[qi][2] * inv + lep.z);
    ov[3] = (_Float16)(acc[qi][3] * inv + lep.w);
    *(f16x4*)(attnh + (size_t)qtok[qi] * 128 + coff + quad * 4) = ov;
  }
}

// ---------------------------------------------------------------------------
// Kernel 3: proj GEMM + bias + residual -> xrh f16.
// 64 tokens/block, 512 threads (8 waves: mq x4, nh x2).
// ---------------------------------------------------------------------------
__global__ __launch_bounds__(512) void k_proj(
    const _Float16* __restrict__ attnh,
    const _Float16* __restrict__ pwh,
    const float* __restrict__ pb,
    const float* __restrict__ x,
    _Float16* __restrict__ xrh)
{
  __shared__ _Float16 as_[64][LS];      // 17920 B
  __shared__ _Float16 wbuf[128][LS];    // 35840 B  (53760)
  const int tid = threadIdx.x;
  const int row0 = blockIdx.x << 6;

#pragma unroll
  for (int it = 0; it < 2; ++it) {
    int id = it * 512 + tid;             // 1024 units
    int r = id >> 4, c8 = id & 15;
    *(uint4*)&as_[r][c8 * 8] = *(const uint4*)(attnh + (size_t)(row0 + r) * 128 + c8 * 8);
  }
#pragma unroll
  for (int it = 0; it < 4; ++it) {
    int id = it * 512 + tid;             // 2048 units
    int r = id >> 4, c8 = id & 15;
    *(uint4*)&wbuf[r][c8 * 8] = *(const uint4*)(pwh + (size_t)r * 128 + c8 * 8);
  }
  __syncthreads();

  const int lane = tid & 63, wave = tid >> 6;
  const int mq = wave & 3, nh = wave >> 2;
  const int m0 = mq << 4, mi = lane & 15, quad = lane >> 4;

  f16x8 afr[4];
#pragma unroll
  for (int kt = 0; kt < 4; ++kt)
    afr[kt] = *(const f16x8*)&as_[m0 + mi][kt * 32 + quad * 8];

  f32x4 acc[4];
#pragma unroll
  for (int nt = 0; nt < 4; ++nt) acc[nt] = (f32x4){0.f, 0.f, 0.f, 0.f};
#pragma unroll
  for (int nt = 0; nt < 4; ++nt) {
    int wrow = (nh * 4 + nt) * 16 + mi;
#pragma unroll
    for (int kt = 0; kt < 4; ++kt) {
      f16x8 bfr = *(const f16x8*)&wbuf[wrow][kt * 32 + quad * 8];
      acc[nt] = __builtin_amdgcn_mfma_f32_16x16x32_f16(afr[kt], bfr, acc[nt], 0, 0, 0);
    }
  }
  __syncthreads();   // all as_ reads done before rewrite
#pragma unroll
  for (int nt = 0; nt < 4; ++nt) {
    int n = (nh * 4 + nt) * 16 + mi;
    float bb = pb[n];
#pragma unroll
    for (int rr = 0; rr < 4; ++rr)
      as_[m0 + quad * 4 + rr][n] = (_Float16)(acc[nt][rr] + bb);
  }
  __syncthreads();

#pragma unroll
  for (int it = 0; it < 2; ++it) {
    int id = it * 512 + tid;
    int r = id >> 4, c8 = id & 15;
    f16x8 v = *(const f16x8*)&as_[r][c8 * 8];
    const float* xp = x + (size_t)(row0 + r) * 128 + c8 * 8;
    float4 xa = *(const float4*)xp;
    float4 xb = *(const float4*)(xp + 4);
    f16x8 o;
    o[0] = (_Float16)((float)v[0] + xa.x); o[1] = (_Float16)((float)v[1] + xa.y);
    o[2] = (_Float16)((float)v[2] + xa.z); o[3] = (_Float16)((float)v[3] + xa.w);
    o[4] = (_Float16)((float)v[4] + xb.x); o[5] = (_Float16)((float)v[5] + xb.y);
    o[6] = (_Float16)((float)v[6] + xb.z); o[7] = (_Float16)((float)v[7] + xb.w);
    *(f16x8*)(xrh + (size_t)(row0 + r) * 128 + c8 * 8) = o;
  }
}

// ---------------------------------------------------------------------------
// Kernel 4: LayerNorm2 + fc1 + sigmoid-GELU + fc2 + residual.
// 64 tokens/block, 512 threads = 8 waves (mt x4, hh x2).
// ---------------------------------------------------------------------------
__global__ __launch_bounds__(512) void k_mlp(
    const _Float16* __restrict__ xrh,
    const float* __restrict__ nw,
    const float* __restrict__ nb,
    const _Float16* __restrict__ w1h,
    const float* __restrict__ f1b,
    const _Float16* __restrict__ w2h,
    const float* __restrict__ f2b,
    float* __restrict__ out)
{
  __shared__ _Float16 xs[64][LS];       // 17920 B
  __shared__ _Float16 wbuf[128][LS];    // 35840 B (also reduce buffer)
  const int tid = threadIdx.x;
  const int row0 = blockIdx.x << 6;

  {
    const int r = tid >> 3, j = tid & 7;
    const _Float16* xp = xrh + (size_t)(row0 + r) * C_ + j * 16;
    float v[16];
#pragma unroll
    for (int i = 0; i < 2; ++i) {
      f16x8 u = ((const f16x8*)xp)[i];
#pragma unroll
      for (int k = 0; k < 8; ++k) v[i * 8 + k] = (float)u[k];
    }
    float s1 = 0.f, s2 = 0.f;
#pragma unroll
    for (int i = 0; i < 16; ++i) { s1 += v[i]; s2 += v[i] * v[i]; }
    s1 += __shfl_down(s1, 4, 8); s1 += __shfl_down(s1, 2, 8); s1 += __shfl_down(s1, 1, 8);
    s2 += __shfl_down(s2, 4, 8); s2 += __shfl_down(s2, 2, 8); s2 += __shfl_down(s2, 1, 8);
    float mu = __shfl(s1, 0, 8) * (1.f / 128.f);
    float ms = __shfl(s2, 0, 8) * (1.f / 128.f);
    float rstd = rsqrtf(ms - mu * mu + 1e-5f);
#pragma unroll
    for (int i = 0; i < 16; ++i) {
      int c = j * 16 + i;
      xs[r][c] = (_Float16)((v[i] - mu) * rstd * nw[c] + nb[c]);
    }
  }
  __syncthreads();

  const int lane = tid & 63, wave = tid >> 6;   // 8 waves
  const int mt = wave & 3, hh = wave >> 2;
  const int tok0 = mt << 4, mi = lane & 15, quad = lane >> 4;

  f16x8 bx[4];
#pragma unroll
  for (int kt = 0; kt < 4; ++kt)
    bx[kt] = *(const f16x8*)&xs[tok0 + mi][kt * 32 + quad * 8];

  f32x4 oacc[8];
#pragma unroll
  for (int o = 0; o < 8; ++o) oacc[o] = (f32x4){0.f, 0.f, 0.f, 0.f};

  // sigmoid-GELU: h * 1/(1 + exp2(-2.4554774 h))
  auto gelu = [](float h) -> float {
    return h * __frcp_rn(1.f + EXP2F(-2.4554774f * h));
  };

  for (int ng = 0; ng < 4; ++ng) {
#pragma unroll
    for (int it = 0; it < 4; ++it) {
      int id = it * 512 + tid;
      int r = id >> 4, c8 = id & 15;
      *(uint4*)&wbuf[r][c8 * 8] = *(const uint4*)(w1h + (size_t)(ng * 128 + r) * 128 + c8 * 8);
    }
    __syncthreads();

    f32x4 hacc[4];
#pragma unroll
    for (int t = 0; t < 4; ++t) hacc[t] = (f32x4){0.f, 0.f, 0.f, 0.f};
#pragma unroll
    for (int t = 0; t < 4; ++t) {
      int hrow = hh * 64 + t * 16 + mi;
#pragma unroll
      for (int kt = 0; kt < 4; ++kt) {
        f16x8 wfr = *(const f16x8*)&wbuf[hrow][kt * 32 + quad * 8];
        hacc[t] = __builtin_amdgcn_mfma_f32_16x16x32_f16(wfr, bx[kt], hacc[t], 0, 0, 0);
      }
    }
    f16x4 ph[4];
#pragma unroll
    for (int t = 0; t < 4; ++t) {
      float4 bj = *(const float4*)(f1b + ng * 128 + hh * 64 + t * 16 + quad * 4);
      ph[t][0] = (_Float16)gelu(hacc[t][0] + bj.x);
      ph[t][1] = (_Float16)gelu(hacc[t][1] + bj.y);
      ph[t][2] = (_Float16)gelu(hacc[t][2] + bj.z);
      ph[t][3] = (_Float16)gelu(hacc[t][3] + bj.w);
    }
    __syncthreads();

#pragma unroll
    for (int it = 0; it < 4; ++it) {
      int id = it * 512 + tid;
      int r = id >> 4, c8 = id & 15;
      *(uint4*)&wbuf[r][c8 * 8] = *(const uint4*)(w2h + (size_t)r * 512 + ng * 128 + c8 * 8);
    }
    __syncthreads();

#pragma unroll
    for (int o = 0; o < 8; ++o) {
#pragma unroll
      for (int t = 0; t < 4; ++t) {
        f16x4 wfr = *(const f16x4*)&wbuf[o * 16 + mi][(hh * 4 + t) * 16 + quad * 4];
        oacc[o] = __builtin_amdgcn_mfma_f32_16x16x16f16(wfr, ph[t], oacc[o], 0, 0, 0);
      }
    }
    __syncthreads();
  }

  float* rbuf = (float*)wbuf;   // 32 * 256 * 4 = 32768 B <= 35840
  if (hh == 1) {
#pragma unroll
    for (int o = 0; o < 8; ++o)
#pragma unroll
      for (int k = 0; k < 4; ++k)
        rbuf[(o * 4 + k) * 256 + mt * 64 + lane] = oacc[o][k];
  }
  __syncthreads();
  if (hh == 0) {
#pragma unroll
    for (int o = 0; o < 8; ++o)
#pragma unroll
      for (int k = 0; k < 4; ++k)
        oacc[o][k] += rbuf[(o * 4 + k) * 256 + mt * 64 + lane];

#pragma unroll
    for (int o = 0; o < 8; ++o) {
      int row = row0 + tok0 + mi;
      int cb4 = o * 16 + quad * 4;
      float4 bo = *(const float4*)(f2b + cb4);
      f16x4 res = *(const f16x4*)(xrh + (size_t)row * C_ + cb4);
      float4 ov;
      ov.x = oacc[o][0] + bo.x + (float)res[0];
      ov.y = oacc[o][1] + bo.y + (float)res[1];
      ov.z = oacc[o][2] + bo.z + (float)res[2];
      ov.w = oacc[o][3] + bo.w + (float)res[3];
      *(float4*)(out + (size_t)row * C_ + cb4) = ov;
    }
  }
}

// ---------------------------------------------------------------------------
extern "C" void kernel_launch(void* const* d_in, const int* in_sizes, int n_in,
                              void* d_out, int out_size, void* d_ws, size_t ws_size,
                              hipStream_t stream)
{
  const float* x    = (const float*)d_in[0];
  const float* n1w  = (const float*)d_in[1];
  const float* n1b  = (const float*)d_in[2];
  const float* qkvw = (const float*)d_in[3];
  const float* cw0  = (const float*)d_in[4];
  const float* cb0  = (const float*)d_in[5];
  const float* cw1  = (const float*)d_in[6];
  const float* cb1  = (const float*)d_in[7];
  const float* pw   = (const float*)d_in[8];
  const float* pb   = (const float*)d_in[9];
  const float* n2w  = (const float*)d_in[10];
  const float* n2b  = (const float*)d_in[11];
  const float* f1w  = (const float*)d_in[12];
  const float* f1b  = (const float*)d_in[13];
  const float* f2w  = (const float*)d_in[14];
  const float* f2b  = (const float*)d_in[15];

  char* ws = (char*)d_ws;
  _Float16* qh    = (_Float16*)ws;                    //  8388608 B
  _Float16* kh    = (_Float16*)(ws +  8388608);       //  8388608 B
  _Float16* vh    = (_Float16*)(ws + 16777216);       //  8388608 B
  _Float16* attnh = (_Float16*)(ws + 25165824);       //  8388608 B
  _Float16* xrh   = (_Float16*)(ws + 33554432);       //  8388608 B
  _Float16* wqh   = (_Float16*)(ws + 41943040);       //    98304 B
  _Float16* pwh   = (_Float16*)(ws + 42041344);       //    32768 B
  _Float16* w1h   = (_Float16*)(ws + 42074112);       //   131072 B
  _Float16* w2h   = (_Float16*)(ws + 42205184);       //   131072 B
  float*    lepw  = (float*)   (ws + 42336256);       //    13824 B

  k_cvt   <<<782,      256, 0, stream>>>(qkvw, pw, f1w, f2w, cw0, cw1,
                                         wqh, pwh, w1h, w2h, lepw);
  k_ln_qkv<<<BL / 64,  512, 0, stream>>>(x, n1w, n1b, wqh, qh, kh, vh);
  k_attn  <<<1024,     512, 0, stream>>>(qh, kh, vh, lepw, cb0, cb1, attnh);
  k_proj  <<<BL / 64,  512, 0, stream>>>(attnh, pwh, pb, x, xrh);
  k_mlp   <<<BL / 64,  512, 0, stream>>>(xrh, n2w, n2b, w1h, f1b, w2h, f2b,
                                         (float*)d_out);
}

// Round 18
// 181.179 us; speedup vs baseline: 1.0531x; 1.0225x over previous
//
#include <hip/hip_runtime.h>
#include <math.h>

// CSWin3DBlock: B=4, T=8, RES=32, C=128. fp32 I/O; f16 MFMA internals.
// LDS stride 140 (<=2-way conflicts on b128 fragment reads).
// k_attn: 512 blocks x 512 threads, 4 qi chains, K/V + V^T staged (57.6 KB).
namespace {
constexpr int C_ = 128;
constexpr int BL = 32768;
constexpr int LS = 140;          // LDS row stride (f16 elems)

typedef __attribute__((ext_vector_type(4))) float f32x4;
typedef __attribute__((ext_vector_type(4))) _Float16 f16x4;
typedef __attribute__((ext_vector_type(8))) _Float16 f16x8;
typedef __attribute__((ext_vector_type(2))) __fp16 hf2;

#if __has_builtin(__builtin_amdgcn_exp2f)
#define EXP2F(x) __builtin_amdgcn_exp2f(x)
#else
#define EXP2F(x) exp2f(x)
#endif
} // namespace

// ---------------------------------------------------------------------------
// Kernel 0: weights fp32 -> f16 row-major (Q rows pre-scaled by 0.25*log2e),
// plus LePE conv-weight transpose to [2][27][64].
// ---------------------------------------------------------------------------
__global__ __launch_bounds__(256) void k_cvt(
    const float* __restrict__ qkvw, const float* __restrict__ pw,
    const float* __restrict__ f1w,  const float* __restrict__ f2w,
    const float* __restrict__ cw0,  const float* __restrict__ cw1,
    _Float16* __restrict__ wqh, _Float16* __restrict__ pwh,
    _Float16* __restrict__ w1h, _Float16* __restrict__ w2h,
    float* __restrict__ lepw)
{
  int i = blockIdx.x * 256 + threadIdx.x;
  if (i < 49152) {
    float v = qkvw[i];
    if (i < 16384) v *= 0.360673762f;    // Q rows: fold 0.25*log2(e)
    wqh[i] = (_Float16)v;
  }
  else if (i < 65536)  pwh[i - 49152] = (_Float16)pw[i - 49152];
  else if (i < 131072) w1h[i - 65536] = (_Float16)f1w[i - 65536];
  else if (i < 196608) w2h[i - 131072] = (_Float16)f2w[i - 131072];
  else if (i < 200064) {
    int j = i - 196608;
    int br = j / 1728, r = j % 1728, widx = r >> 6, ch = r & 63;
    lepw[j] = (br ? cw1 : cw0)[ch * 27 + widx];
  }
}

// ---------------------------------------------------------------------------
// Kernel 1: LayerNorm1 + QKV GEMM + windowed scatter.
// 64 tokens/block, 512 threads (8 waves: mq x4, nh x2).  (R17, passing)
// ---------------------------------------------------------------------------
__global__ __launch_bounds__(512) void k_ln_qkv(
    const float* __restrict__ x,
    const float* __restrict__ nw,
    const float* __restrict__ nb,
    const _Float16* __restrict__ wqh,
    _Float16* __restrict__ qh, _Float16* __restrict__ kh, _Float16* __restrict__ vh)
{
  __shared__ _Float16 xs[64][LS];      // 17920 B
  __shared__ _Float16 qt[64][LS];      // 17920 B
  __shared__ _Float16 wbuf[128][LS];   // 35840 B  (total 71680)
  const int tid = threadIdx.x;
  const int row0 = blockIdx.x << 6;
  const int bb = row0 >> 13, t = (row0 >> 10) & 7, h0 = (row0 >> 5) & 31;
  const int tb = t >> 2, t_in = t & 3;

  {
    const int r = tid >> 3, j = tid & 7;
    const float* xp = x + (size_t)(row0 + r) * C_ + j * 16;
    float v[16];
#pragma unroll
    for (int i = 0; i < 4; ++i) {
      float4 u = ((const float4*)xp)[i];
      v[i*4+0] = u.x; v[i*4+1] = u.y; v[i*4+2] = u.z; v[i*4+3] = u.w;
    }
    float s1 = 0.f, s2 = 0.f;
#pragma unroll
    for (int i = 0; i < 16; ++i) { s1 += v[i]; s2 += v[i] * v[i]; }
    s1 += __shfl_down(s1, 4, 8); s1 += __shfl_down(s1, 2, 8); s1 += __shfl_down(s1, 1, 8);
    s2 += __shfl_down(s2, 4, 8); s2 += __shfl_down(s2, 2, 8); s2 += __shfl_down(s2, 1, 8);
    float mu = __shfl(s1, 0, 8) * (1.f / 128.f);
    float ms = __shfl(s2, 0, 8) * (1.f / 128.f);
    float rstd = rsqrtf(ms - mu * mu + 1e-5f);
#pragma unroll
    for (int i = 0; i < 16; ++i) {
      int c = j * 16 + i;
      xs[r][c] = (_Float16)((v[i] - mu) * rstd * nw[c] + nb[c]);
    }
  }
  __syncthreads();

  const int lane = tid & 63, wave = tid >> 6;   // 8 waves
  const int mq = wave & 3, nh = wave >> 2;
  const int m0 = mq << 4, mi = lane & 15, quad = lane >> 4;

  f16x8 afr[4];
#pragma unroll
  for (int kt = 0; kt < 4; ++kt)
    afr[kt] = *(const f16x8*)&xs[m0 + mi][kt * 32 + quad * 8];

  for (int g = 0; g < 3; ++g) {
#pragma unroll
    for (int it = 0; it < 4; ++it) {
      int id = it * 512 + tid;           // 2048 units
      int r = id >> 4, c8 = id & 15;
      *(uint4*)&wbuf[r][c8 * 8] = *(const uint4*)(wqh + (size_t)(g * 128 + r) * 128 + c8 * 8);
    }
    __syncthreads();

    f32x4 acc[4];
#pragma unroll
    for (int nt = 0; nt < 4; ++nt) acc[nt] = (f32x4){0.f, 0.f, 0.f, 0.f};
#pragma unroll
    for (int nt = 0; nt < 4; ++nt) {
      int wrow = (nh * 4 + nt) * 16 + mi;
#pragma unroll
      for (int kt = 0; kt < 4; ++kt) {
        f16x8 bfr = *(const f16x8*)&wbuf[wrow][kt * 32 + quad * 8];
        acc[nt] = __builtin_amdgcn_mfma_f32_16x16x32_f16(afr[kt], bfr, acc[nt], 0, 0, 0);
      }
    }
#pragma unroll
    for (int nt = 0; nt < 4; ++nt) {
      int n = (nh * 4 + nt) * 16 + mi;
#pragma unroll
      for (int rr = 0; rr < 4; ++rr)
        qt[m0 + quad * 4 + rr][n] = (_Float16)acc[nt][rr];
    }
    __syncthreads();

    _Float16* G = (g == 0) ? qh : (g == 1) ? kh : vh;
#pragma unroll
    for (int it = 0; it < 2; ++it) {
      int u = it * 512 + tid;            // 1024 units of 16 B
      if (u < 512) {                     // branch 0: Hsp=32, Wsp=4
        int half = u & 1, p = (u >> 1) & 7, head = (u >> 4) & 3, sb = u >> 6;
        int token = (p >> 2) * 32 + sb * 4 + (p & 3);
        uint4 d = *(const uint4*)&qt[token][head * 16 + half * 8];
        int win = bb * 16 + tb * 8 + sb;
        int pos = t_in * 128 + h0 * 4 + p;
        *(uint4*)(G + ((size_t)(head * 64 + win) * 512 + pos) * 16 + half * 8) = d;
      } else {                           // branch 1: Hsp=4, Wsp=32
        int u2 = u - 512;
        int half = u2 & 1, pin = (u2 >> 1) & 63, head = u2 >> 7;
        uint4 d = *(const uint4*)&qt[pin][64 + head * 16 + half * 8];
        int win = bb * 16 + tb * 8 + (h0 >> 2);
        int pos = t_in * 128 + (h0 & 3) * 32 + pin;
        *(uint4*)(G + ((size_t)((4 + head) * 64 + win) * 512 + pos) * 16 + half * 8) = d;
      }
    }
    __syncthreads();
  }
}

// ---------------------------------------------------------------------------
// Kernel 2: MFMA flash attention + LePE.  512 blocks x 512 threads,
// 4 qi chains per wave (R14 shape) + V^T buffer for b64 PV A-fragment loads.
// LDS 57600 B -> 2 blocks/CU.
// ---------------------------------------------------------------------------
__global__ __launch_bounds__(512) void k_attn(
    const _Float16* __restrict__ qh,
    const _Float16* __restrict__ kh,
    const _Float16* __restrict__ vh,
    const float* __restrict__ lepw,
    const float* __restrict__ cb0,
    const float* __restrict__ cb1,
    _Float16* __restrict__ attnh)
{
  __shared__ _Float16 Ks[512][20];     // 20480 B
  __shared__ _Float16 Vs[512][20];     // 20480 B
  __shared__ _Float16 Vt[16][520];     // 16640 B (PV A-operand)

  const int tid = threadIdx.x;
  const int bid = blockIdx.x;
  const int br = bid >> 8, wi = (bid >> 2) & 63, head = bid & 3;
  const int b = wi >> 4, tb = (wi >> 3) & 1, sb = wi & 7;
  const int coff = br * 64 + head * 16;
  const int Hsp = br ? 4 : 32, Wsp = br ? 32 : 4;
  const float* cb = br ? cb1 : cb0;
  const size_t base = ((size_t)(br * 4 + head) * 64 + wi) * 512 * 16;

  auto token_of = [&](int p) -> int {
    int t_in = p >> 7;
    int rem = p & 127;
    int h, w;
    if (br == 0) { h = rem >> 2;            w = sb * 4 + (rem & 3); }
    else         { h = sb * 4 + (rem >> 5); w = rem & 31; }
    return ((b * 8 + tb * 4 + t_in) << 10) + (h << 5) + w;
  };

  {
    const int r = tid;
    const _Float16* kp = kh + base + r * 16;
    const _Float16* vp = vh + base + r * 16;
    f16x8 k0 = *(const f16x8*)kp;
    f16x8 k1 = *(const f16x8*)(kp + 8);
    f16x8 v0 = *(const f16x8*)vp;
    f16x8 v1 = *(const f16x8*)(vp + 8);
    *(f16x4*)&Ks[r][0]  = (f16x4){k0[0], k0[1], k0[2], k0[3]};
    *(f16x4*)&Ks[r][4]  = (f16x4){k0[4], k0[5], k0[6], k0[7]};
    *(f16x4*)&Ks[r][8]  = (f16x4){k1[0], k1[1], k1[2], k1[3]};
    *(f16x4*)&Ks[r][12] = (f16x4){k1[4], k1[5], k1[6], k1[7]};
    *(f16x4*)&Vs[r][0]  = (f16x4){v0[0], v0[1], v0[2], v0[3]};
    *(f16x4*)&Vs[r][4]  = (f16x4){v0[4], v0[5], v0[6], v0[7]};
    *(f16x4*)&Vs[r][8]  = (f16x4){v1[0], v1[1], v1[2], v1[3]};
    *(f16x4*)&Vs[r][12] = (f16x4){v1[4], v1[5], v1[6], v1[7]};
#pragma unroll
    for (int d = 0; d < 8; ++d) { Vt[d][r] = v0[d]; Vt[d + 8][r] = v1[d]; }
  }

  const int lane = tid & 63, wave = tid >> 6;   // 8 waves
  const int mi = lane & 15, quad = lane >> 4;

  int qtok[4];
  f16x4 qfr[4];
#pragma unroll
  for (int qi = 0; qi < 4; ++qi) {
    int q = (wave * 4 + qi) * 16 + mi;
    qtok[qi] = token_of(q);
    qfr[qi] = *(const f16x4*)(qh + base + q * 16 + quad * 4);
  }
  __syncthreads();

  f32x4 acc[4];
  float l[4];
#pragma unroll
  for (int qi = 0; qi < 4; ++qi) { acc[qi] = (f32x4){0.f,0.f,0.f,0.f}; l[qi] = 0.f; }

  const hf2 one2 = {(__fp16)1.f, (__fp16)1.f};

  for (int kt = 0; kt < 32; ++kt) {
    const int kb = kt << 4;
    f16x4 kfr = *(const f16x4*)&Ks[kb + mi][quad * 4];
    f16x4 vfr = *(const f16x4*)&Vt[mi][kb + quad * 4];
#pragma unroll
    for (int qi = 0; qi < 4; ++qi) {
      f32x4 s = __builtin_amdgcn_mfma_f32_16x16x16f16(kfr, qfr[qi], (f32x4){0.f,0.f,0.f,0.f}, 0, 0, 0);
      float p0 = EXP2F(s[0]);
      float p1 = EXP2F(s[1]);
      float p2 = EXP2F(s[2]);
      float p3 = EXP2F(s[3]);
      hf2 plo = __builtin_amdgcn_cvt_pkrtz(p0, p1);
      hf2 phi = __builtin_amdgcn_cvt_pkrtz(p2, p3);
#if __has_builtin(__builtin_amdgcn_fdot2)
      l[qi] = __builtin_amdgcn_fdot2(plo, one2, l[qi], false);
      l[qi] = __builtin_amdgcn_fdot2(phi, one2, l[qi], false);
#else
      l[qi] += (p0 + p1) + (p2 + p3);
#endif
      union { struct { hf2 lo, hi; } h; f16x4 v; } u;
      u.h.lo = plo; u.h.hi = phi;
      acc[qi] = __builtin_amdgcn_mfma_f32_16x16x16f16(vfr, u.v, acc[qi], 0, 0, 0);
    }
  }

#pragma unroll
  for (int qi = 0; qi < 4; ++qi) {
    float lq = l[qi];
    lq += __shfl_xor(lq, 16, 64);
    lq += __shfl_xor(lq, 32, 64);
    float inv = 1.f / lq;

    const int q = (wave * 4 + qi) * 16 + mi;
    int t_in = q >> 7, rem = q & 127;
    int h_in, w_in;
    if (br == 0) { h_in = rem >> 2; w_in = rem & 3; }
    else         { h_in = rem >> 5; w_in = rem & 31; }
    float4 lep = *(const float4*)(cb + head * 16 + quad * 4);
    for (int dz = 0; dz < 3; ++dz) {
      int tz = t_in + dz - 1; if ((unsigned)tz >= 4u) continue;
      for (int dy = 0; dy < 3; ++dy) {
        int ty = h_in + dy - 1; if ((unsigned)ty >= (unsigned)Hsp) continue;
        for (int dx = 0; dx < 3; ++dx) {
          int tx = w_in + dx - 1; if ((unsigned)tx >= (unsigned)Wsp) continue;
          int np = (tz * Hsp + ty) * Wsp + tx;
          int widx = (dz * 3 + dy) * 3 + dx;
          float4 w4 = *(const float4*)(lepw + ((br * 27 + widx) << 6) + head * 16 + quad * 4);
          f16x4 vv = *(const f16x4*)&Vs[np][quad * 4];
          lep.x += w4.x * (float)vv[0];
          lep.y += w4.y * (float)vv[1];
          lep.z += w4.z * (float)vv[2];
          lep.w += w4.w * (float)vv[3];
        }
      }
    }
    f16x4 ov;
    ov[0] = (_Float16)(acc[qi][0] * inv + lep.x);
    ov[1] = (_Float16)(acc[qi][1] * inv + lep.y);
    ov[2] = (_Float16)(acc[qi][2] * inv + lep.z);
    ov[3] = (_Float16)(acc[qi][3] * inv + lep.w);
    *(f16x4*)(attnh + (size_t)qtok[qi] * 128 + coff + quad * 4) = ov;
  }
}

// ---------------------------------------------------------------------------
// Kernel 3: proj GEMM + bias + residual -> xrh f16.
// 64 tokens/block, 512 threads (8 waves: mq x4, nh x2).  (R17, passing)
// ---------------------------------------------------------------------------
__global__ __launch_bounds__(512) void k_proj(
    const _Float16* __restrict__ attnh,
    const _Float16* __restrict__ pwh,
    const float* __restrict__ pb,
    const float* __restrict__ x,
    _Float16* __restrict__ xrh)
{
  __shared__ _Float16 as_[64][LS];      // 17920 B
  __shared__ _Float16 wbuf[128][LS];    // 35840 B  (53760)
  const int tid = threadIdx.x;
  const int row0 = blockIdx.x << 6;

#pragma unroll
  for (int it = 0; it < 2; ++it) {
    int id = it * 512 + tid;             // 1024 units
    int r = id >> 4, c8 = id & 15;
    *(uint4*)&as_[r][c8 * 8] = *(const uint4*)(attnh + (size_t)(row0 + r) * 128 + c8 * 8);
  }
#pragma unroll
  for (int it = 0; it < 4; ++it) {
    int id = it * 512 + tid;             // 2048 units
    int r = id >> 4, c8 = id & 15;
    *(uint4*)&wbuf[r][c8 * 8] = *(const uint4*)(pwh + (size_t)r * 128 + c8 * 8);
  }
  __syncthreads();

  const int lane = tid & 63, wave = tid >> 6;
  const int mq = wave & 3, nh = wave >> 2;
  const int m0 = mq << 4, mi = lane & 15, quad = lane >> 4;

  f16x8 afr[4];
#pragma unroll
  for (int kt = 0; kt < 4; ++kt)
    afr[kt] = *(const f16x8*)&as_[m0 + mi][kt * 32 + quad * 8];

  f32x4 acc[4];
#pragma unroll
  for (int nt = 0; nt < 4; ++nt) acc[nt] = (f32x4){0.f, 0.f, 0.f, 0.f};
#pragma unroll
  for (int nt = 0; nt < 4; ++nt) {
    int wrow = (nh * 4 + nt) * 16 + mi;
#pragma unroll
    for (int kt = 0; kt < 4; ++kt) {
      f16x8 bfr = *(const f16x8*)&wbuf[wrow][kt * 32 + quad * 8];
      acc[nt] = __builtin_amdgcn_mfma_f32_16x16x32_f16(afr[kt], bfr, acc[nt], 0, 0, 0);
    }
  }
  __syncthreads();   // all as_ reads done before rewrite
#pragma unroll
  for (int nt = 0; nt < 4; ++nt) {
    int n = (nh * 4 + nt) * 16 + mi;
    float bb = pb[n];
#pragma unroll
    for (int rr = 0; rr < 4; ++rr)
      as_[m0 + quad * 4 + rr][n] = (_Float16)(acc[nt][rr] + bb);
  }
  __syncthreads();

#pragma unroll
  for (int it = 0; it < 2; ++it) {
    int id = it * 512 + tid;
    int r = id >> 4, c8 = id & 15;
    f16x8 v = *(const f16x8*)&as_[r][c8 * 8];
    const float* xp = x + (size_t)(row0 + r) * 128 + c8 * 8;
    float4 xa = *(const float4*)xp;
    float4 xb = *(const float4*)(xp + 4);
    f16x8 o;
    o[0] = (_Float16)((float)v[0] + xa.x); o[1] = (_Float16)((float)v[1] + xa.y);
    o[2] = (_Float16)((float)v[2] + xa.z); o[3] = (_Float16)((float)v[3] + xa.w);
    o[4] = (_Float16)((float)v[4] + xb.x); o[5] = (_Float16)((float)v[5] + xb.y);
    o[6] = (_Float16)((float)v[6] + xb.z); o[7] = (_Float16)((float)v[7] + xb.w);
    *(f16x8*)(xrh + (size_t)(row0 + r) * 128 + c8 * 8) = o;
  }
}

// ---------------------------------------------------------------------------
// Kernel 4: LayerNorm2 + fc1 + sigmoid-GELU + fc2 + residual.  (R17, passing)
// 64 tokens/block, 512 threads = 8 waves (mt x4, hh x2).
// ---------------------------------------------------------------------------
__global__ __launch_bounds__(512) void k_mlp(
    const _Float16* __restrict__ xrh,
    const float* __restrict__ nw,
    const float* __restrict__ nb,
    const _Float16* __restrict__ w1h,
    const float* __restrict__ f1b,
    const _Float16* __restrict__ w2h,
    const float* __restrict__ f2b,
    float* __restrict__ out)
{
  __shared__ _Float16 xs[64][LS];       // 17920 B
  __shared__ _Float16 wbuf[128][LS];    // 35840 B (also reduce buffer)
  const int tid = threadIdx.x;
  const int row0 = blockIdx.x << 6;

  {
    const int r = tid >> 3, j = tid & 7;
    const _Float16* xp = xrh + (size_t)(row0 + r) * C_ + j * 16;
    float v[16];
#pragma unroll
    for (int i = 0; i < 2; ++i) {
      f16x8 u = ((const f16x8*)xp)[i];
#pragma unroll
      for (int k = 0; k < 8; ++k) v[i * 8 + k] = (float)u[k];
    }
    float s1 = 0.f, s2 = 0.f;
#pragma unroll
    for (int i = 0; i < 16; ++i) { s1 += v[i]; s2 += v[i] * v[i]; }
    s1 += __shfl_down(s1, 4, 8); s1 += __shfl_down(s1, 2, 8); s1 += __shfl_down(s1, 1, 8);
    s2 += __shfl_down(s2, 4, 8); s2 += __shfl_down(s2, 2, 8); s2 += __shfl_down(s2, 1, 8);
    float mu = __shfl(s1, 0, 8) * (1.f / 128.f);
    float ms = __shfl(s2, 0, 8) * (1.f / 128.f);
    float rstd = rsqrtf(ms - mu * mu + 1e-5f);
#pragma unroll
    for (int i = 0; i < 16; ++i) {
      int c = j * 16 + i;
      xs[r][c] = (_Float16)((v[i] - mu) * rstd * nw[c] + nb[c]);
    }
  }
  __syncthreads();

  const int lane = tid & 63, wave = tid >> 6;   // 8 waves
  const int mt = wave & 3, hh = wave >> 2;
  const int tok0 = mt << 4, mi = lane & 15, quad = lane >> 4;

  f16x8 bx[4];
#pragma unroll
  for (int kt = 0; kt < 4; ++kt)
    bx[kt] = *(const f16x8*)&xs[tok0 + mi][kt * 32 + quad * 8];

  f32x4 oacc[8];
#pragma unroll
  for (int o = 0; o < 8; ++o) oacc[o] = (f32x4){0.f, 0.f, 0.f, 0.f};

  auto gelu = [](float h) -> float {
    return h * __frcp_rn(1.f + EXP2F(-2.4554774f * h));
  };

  for (int ng = 0; ng < 4; ++ng) {
#pragma unroll
    for (int it = 0; it < 4; ++it) {
      int id = it * 512 + tid;
      int r = id >> 4, c8 = id & 15;
      *(uint4*)&wbuf[r][c8 * 8] = *(const uint4*)(w1h + (size_t)(ng * 128 + r) * 128 + c8 * 8);
    }
    __syncthreads();

    f32x4 hacc[4];
#pragma unroll
    for (int t = 0; t < 4; ++t) hacc[t] = (f32x4){0.f, 0.f, 0.f, 0.f};
#pragma unroll
    for (int t = 0; t < 4; ++t) {
      int hrow = hh * 64 + t * 16 + mi;
#pragma unroll
      for (int kt = 0; kt < 4; ++kt) {
        f16x8 wfr = *(const f16x8*)&wbuf[hrow][kt * 32 + quad * 8];
        hacc[t] = __builtin_amdgcn_mfma_f32_16x16x32_f16(wfr, bx[kt], hacc[t], 0, 0, 0);
      }
    }
    f16x4 ph[4];
#pragma unroll
    for (int t = 0; t < 4; ++t) {
      float4 bj = *(const float4*)(f1b + ng * 128 + hh * 64 + t * 16 + quad * 4);
      ph[t][0] = (_Float16)gelu(hacc[t][0] + bj.x);
      ph[t][1] = (_Float16)gelu(hacc[t][1] + bj.y);
      ph[t][2] = (_Float16)gelu(hacc[t][2] + bj.z);
      ph[t][3] = (_Float16)gelu(hacc[t][3] + bj.w);
    }
    __syncthreads();

#pragma unroll
    for (int it = 0; it < 4; ++it) {
      int id = it * 512 + tid;
      int r = id >> 4, c8 = id & 15;
      *(uint4*)&wbuf[r][c8 * 8] = *(const uint4*)(w2h + (size_t)r * 512 + ng * 128 + c8 * 8);
    }
    __syncthreads();

#pragma unroll
    for (int o = 0; o < 8; ++o) {
#pragma unroll
      for (int t = 0; t < 4; ++t) {
        f16x4 wfr = *(const f16x4*)&wbuf[o * 16 + mi][(hh * 4 + t) * 16 + quad * 4];
        oacc[o] = __builtin_amdgcn_mfma_f32_16x16x16f16(wfr, ph[t], oacc[o], 0, 0, 0);
      }
    }
    __syncthreads();
  }

  float* rbuf = (float*)wbuf;   // 32 * 256 * 4 = 32768 B <= 35840
  if (hh == 1) {
#pragma unroll
    for (int o = 0; o < 8; ++o)
#pragma unroll
      for (int k = 0; k < 4; ++k)
        rbuf[(o * 4 + k) * 256 + mt * 64 + lane] = oacc[o][k];
  }
  __syncthreads();
  if (hh == 0) {
#pragma unroll
    for (int o = 0; o < 8; ++o)
#pragma unroll
      for (int k = 0; k < 4; ++k)
        oacc[o][k] += rbuf[(o * 4 + k) * 256 + mt * 64 + lane];

#pragma unroll
    for (int o = 0; o < 8; ++o) {
      int row = row0 + tok0 + mi;
      int cb4 = o * 16 + quad * 4;
      float4 bo = *(const float4*)(f2b + cb4);
      f16x4 res = *(const f16x4*)(xrh + (size_t)row * C_ + cb4);
      float4 ov;
      ov.x = oacc[o][0] + bo.x + (float)res[0];
      ov.y = oacc[o][1] + bo.y + (float)res[1];
      ov.z = oacc[o][2] + bo.z + (float)res[2];
      ov.w = oacc[o][3] + bo.w + (float)res[3];
      *(float4*)(out + (size_t)row * C_ + cb4) = ov;
    }
  }
}

// ---------------------------------------------------------------------------
extern "C" void kernel_launch(void* const* d_in, const int* in_sizes, int n_in,
                              void* d_out, int out_size, void* d_ws, size_t ws_size,
                              hipStream_t stream)
{
  const float* x    = (const float*)d_in[0];
  const float* n1w  = (const float*)d_in[1];
  const float* n1b  = (const float*)d_in[2];
  const float* qkvw = (const float*)d_in[3];
  const float* cw0  = (const float*)d_in[4];
  const float* cb0  = (const float*)d_in[5];
  const float* cw1  = (const float*)d_in[6];
  const float* cb1  = (const float*)d_in[7];
  const float* pw   = (const float*)d_in[8];
  const float* pb   = (const float*)d_in[9];
  const float* n2w  = (const float*)d_in[10];
  const float* n2b  = (const float*)d_in[11];
  const float* f1w  = (const float*)d_in[12];
  const float* f1b  = (const float*)d_in[13];
  const float* f2w  = (const float*)d_in[14];
  const float* f2b  = (const float*)d_in[15];

  char* ws = (char*)d_ws;
  _Float16* qh    = (_Float16*)ws;                    //  8388608 B
  _Float16* kh    = (_Float16*)(ws +  8388608);       //  8388608 B
  _Float16* vh    = (_Float16*)(ws + 16777216);       //  8388608 B
  _Float16* attnh = (_Float16*)(ws + 25165824);       //  8388608 B
  _Float16* xrh   = (_Float16*)(ws + 33554432);       //  8388608 B
  _Float16* wqh   = (_Float16*)(ws + 41943040);       //    98304 B
  _Float16* pwh   = (_Float16*)(ws + 42041344);       //    32768 B
  _Float16* w1h   = (_Float16*)(ws + 42074112);       //   131072 B
  _Float16* w2h   = (_Float16*)(ws + 42205184);       //   131072 B
  float*    lepw  = (float*)   (ws + 42336256);       //    13824 B

  k_cvt   <<<782,      256, 0, stream>>>(qkvw, pw, f1w, f2w, cw0, cw1,
                                         wqh, pwh, w1h, w2h, lepw);
  k_ln_qkv<<<BL / 64,  512, 0, stream>>>(x, n1w, n1b, wqh, qh, kh, vh);
  k_attn  <<<512,      512, 0, stream>>>(qh, kh, vh, lepw, cb0, cb1, attnh);
  k_proj  <<<BL / 64,  512, 0, stream>>>(attnh, pwh, pb, x, xrh);
  k_mlp   <<<BL / 64,  512, 0, stream>>>(xrh, n2w, n2b, w1h, f1b, w2h, f2b,
                                         (float*)d_out);
}

// Round 19
// 174.236 us; speedup vs baseline: 1.0951x; 1.0398x over previous
//
#include <hip/hip_runtime.h>
#include <math.h>

// CSWin3DBlock: B=4, T=8, RES=32, C=128. fp32 I/O; f16 MFMA internals.
// LDS stride 140.  k_pm fuses proj + residual + LN2 + MLP (xr lives in LDS).
namespace {
constexpr int C_ = 128;
constexpr int BL = 32768;
constexpr int LS = 140;          // LDS row stride (f16 elems)

typedef __attribute__((ext_vector_type(4))) float f32x4;
typedef __attribute__((ext_vector_type(4))) _Float16 f16x4;
typedef __attribute__((ext_vector_type(8))) _Float16 f16x8;
typedef __attribute__((ext_vector_type(2))) __fp16 hf2;

#if __has_builtin(__builtin_amdgcn_exp2f)
#define EXP2F(x) __builtin_amdgcn_exp2f(x)
#else
#define EXP2F(x) exp2f(x)
#endif
} // namespace

// ---------------------------------------------------------------------------
// Kernel 0: weights fp32 -> f16 row-major (Q rows pre-scaled by 0.25*log2e),
// plus LePE conv-weight transpose to [2][27][64].
// ---------------------------------------------------------------------------
__global__ __launch_bounds__(256) void k_cvt(
    const float* __restrict__ qkvw, const float* __restrict__ pw,
    const float* __restrict__ f1w,  const float* __restrict__ f2w,
    const float* __restrict__ cw0,  const float* __restrict__ cw1,
    _Float16* __restrict__ wqh, _Float16* __restrict__ pwh,
    _Float16* __restrict__ w1h, _Float16* __restrict__ w2h,
    float* __restrict__ lepw)
{
  int i = blockIdx.x * 256 + threadIdx.x;
  if (i < 49152) {
    float v = qkvw[i];
    if (i < 16384) v *= 0.360673762f;    // Q rows: fold 0.25*log2(e)
    wqh[i] = (_Float16)v;
  }
  else if (i < 65536)  pwh[i - 49152] = (_Float16)pw[i - 49152];
  else if (i < 131072) w1h[i - 65536] = (_Float16)f1w[i - 65536];
  else if (i < 196608) w2h[i - 131072] = (_Float16)f2w[i - 131072];
  else if (i < 200064) {
    int j = i - 196608;
    int br = j / 1728, r = j % 1728, widx = r >> 6, ch = r & 63;
    lepw[j] = (br ? cw1 : cw0)[ch * 27 + widx];
  }
}

// ---------------------------------------------------------------------------
// Kernel 1: LayerNorm1 + QKV GEMM + windowed scatter.  (R18, passing)
// ---------------------------------------------------------------------------
__global__ __launch_bounds__(512) void k_ln_qkv(
    const float* __restrict__ x,
    const float* __restrict__ nw,
    const float* __restrict__ nb,
    const _Float16* __restrict__ wqh,
    _Float16* __restrict__ qh, _Float16* __restrict__ kh, _Float16* __restrict__ vh)
{
  __shared__ _Float16 xs[64][LS];      // 17920 B
  __shared__ _Float16 qt[64][LS];      // 17920 B
  __shared__ _Float16 wbuf[128][LS];   // 35840 B  (total 71680)
  const int tid = threadIdx.x;
  const int row0 = blockIdx.x << 6;
  const int bb = row0 >> 13, t = (row0 >> 10) & 7, h0 = (row0 >> 5) & 31;
  const int tb = t >> 2, t_in = t & 3;

  {
    const int r = tid >> 3, j = tid & 7;
    const float* xp = x + (size_t)(row0 + r) * C_ + j * 16;
    float v[16];
#pragma unroll
    for (int i = 0; i < 4; ++i) {
      float4 u = ((const float4*)xp)[i];
      v[i*4+0] = u.x; v[i*4+1] = u.y; v[i*4+2] = u.z; v[i*4+3] = u.w;
    }
    float s1 = 0.f, s2 = 0.f;
#pragma unroll
    for (int i = 0; i < 16; ++i) { s1 += v[i]; s2 += v[i] * v[i]; }
    s1 += __shfl_down(s1, 4, 8); s1 += __shfl_down(s1, 2, 8); s1 += __shfl_down(s1, 1, 8);
    s2 += __shfl_down(s2, 4, 8); s2 += __shfl_down(s2, 2, 8); s2 += __shfl_down(s2, 1, 8);
    float mu = __shfl(s1, 0, 8) * (1.f / 128.f);
    float ms = __shfl(s2, 0, 8) * (1.f / 128.f);
    float rstd = rsqrtf(ms - mu * mu + 1e-5f);
#pragma unroll
    for (int i = 0; i < 16; ++i) {
      int c = j * 16 + i;
      xs[r][c] = (_Float16)((v[i] - mu) * rstd * nw[c] + nb[c]);
    }
  }
  __syncthreads();

  const int lane = tid & 63, wave = tid >> 6;   // 8 waves
  const int mq = wave & 3, nh = wave >> 2;
  const int m0 = mq << 4, mi = lane & 15, quad = lane >> 4;

  f16x8 afr[4];
#pragma unroll
  for (int kt = 0; kt < 4; ++kt)
    afr[kt] = *(const f16x8*)&xs[m0 + mi][kt * 32 + quad * 8];

  for (int g = 0; g < 3; ++g) {
#pragma unroll
    for (int it = 0; it < 4; ++it) {
      int id = it * 512 + tid;           // 2048 units
      int r = id >> 4, c8 = id & 15;
      *(uint4*)&wbuf[r][c8 * 8] = *(const uint4*)(wqh + (size_t)(g * 128 + r) * 128 + c8 * 8);
    }
    __syncthreads();

    f32x4 acc[4];
#pragma unroll
    for (int nt = 0; nt < 4; ++nt) acc[nt] = (f32x4){0.f, 0.f, 0.f, 0.f};
#pragma unroll
    for (int nt = 0; nt < 4; ++nt) {
      int wrow = (nh * 4 + nt) * 16 + mi;
#pragma unroll
      for (int kt = 0; kt < 4; ++kt) {
        f16x8 bfr = *(const f16x8*)&wbuf[wrow][kt * 32 + quad * 8];
        acc[nt] = __builtin_amdgcn_mfma_f32_16x16x32_f16(afr[kt], bfr, acc[nt], 0, 0, 0);
      }
    }
#pragma unroll
    for (int nt = 0; nt < 4; ++nt) {
      int n = (nh * 4 + nt) * 16 + mi;
#pragma unroll
      for (int rr = 0; rr < 4; ++rr)
        qt[m0 + quad * 4 + rr][n] = (_Float16)acc[nt][rr];
    }
    __syncthreads();

    _Float16* G = (g == 0) ? qh : (g == 1) ? kh : vh;
#pragma unroll
    for (int it = 0; it < 2; ++it) {
      int u = it * 512 + tid;            // 1024 units of 16 B
      if (u < 512) {                     // branch 0: Hsp=32, Wsp=4
        int half = u & 1, p = (u >> 1) & 7, head = (u >> 4) & 3, sb = u >> 6;
        int token = (p >> 2) * 32 + sb * 4 + (p & 3);
        uint4 d = *(const uint4*)&qt[token][head * 16 + half * 8];
        int win = bb * 16 + tb * 8 + sb;
        int pos = t_in * 128 + h0 * 4 + p;
        *(uint4*)(G + ((size_t)(head * 64 + win) * 512 + pos) * 16 + half * 8) = d;
      } else {                           // branch 1: Hsp=4, Wsp=32
        int u2 = u - 512;
        int half = u2 & 1, pin = (u2 >> 1) & 63, head = u2 >> 7;
        uint4 d = *(const uint4*)&qt[pin][64 + head * 16 + half * 8];
        int win = bb * 16 + tb * 8 + (h0 >> 2);
        int pos = t_in * 128 + (h0 & 3) * 32 + pin;
        *(uint4*)(G + ((size_t)((4 + head) * 64 + win) * 512 + pos) * 16 + half * 8) = d;
      }
    }
    __syncthreads();
  }
}

// ---------------------------------------------------------------------------
// Kernel 2: MFMA flash attention + LePE.  (R18, passing)
// 512 blocks x 512 threads, 4 qi chains + V^T buffer.  LDS 57600 B.
// ---------------------------------------------------------------------------
__global__ __launch_bounds__(512) void k_attn(
    const _Float16* __restrict__ qh,
    const _Float16* __restrict__ kh,
    const _Float16* __restrict__ vh,
    const float* __restrict__ lepw,
    const float* __restrict__ cb0,
    const float* __restrict__ cb1,
    _Float16* __restrict__ attnh)
{
  __shared__ _Float16 Ks[512][20];
  __shared__ _Float16 Vs[512][20];
  __shared__ _Float16 Vt[16][520];

  const int tid = threadIdx.x;
  const int bid = blockIdx.x;
  const int br = bid >> 8, wi = (bid >> 2) & 63, head = bid & 3;
  const int b = wi >> 4, tb = (wi >> 3) & 1, sb = wi & 7;
  const int coff = br * 64 + head * 16;
  const int Hsp = br ? 4 : 32, Wsp = br ? 32 : 4;
  const float* cb = br ? cb1 : cb0;
  const size_t base = ((size_t)(br * 4 + head) * 64 + wi) * 512 * 16;

  auto token_of = [&](int p) -> int {
    int t_in = p >> 7;
    int rem = p & 127;
    int h, w;
    if (br == 0) { h = rem >> 2;            w = sb * 4 + (rem & 3); }
    else         { h = sb * 4 + (rem >> 5); w = rem & 31; }
    return ((b * 8 + tb * 4 + t_in) << 10) + (h << 5) + w;
  };

  {
    const int r = tid;
    const _Float16* kp = kh + base + r * 16;
    const _Float16* vp = vh + base + r * 16;
    f16x8 k0 = *(const f16x8*)kp;
    f16x8 k1 = *(const f16x8*)(kp + 8);
    f16x8 v0 = *(const f16x8*)vp;
    f16x8 v1 = *(const f16x8*)(vp + 8);
    *(f16x4*)&Ks[r][0]  = (f16x4){k0[0], k0[1], k0[2], k0[3]};
    *(f16x4*)&Ks[r][4]  = (f16x4){k0[4], k0[5], k0[6], k0[7]};
    *(f16x4*)&Ks[r][8]  = (f16x4){k1[0], k1[1], k1[2], k1[3]};
    *(f16x4*)&Ks[r][12] = (f16x4){k1[4], k1[5], k1[6], k1[7]};
    *(f16x4*)&Vs[r][0]  = (f16x4){v0[0], v0[1], v0[2], v0[3]};
    *(f16x4*)&Vs[r][4]  = (f16x4){v0[4], v0[5], v0[6], v0[7]};
    *(f16x4*)&Vs[r][8]  = (f16x4){v1[0], v1[1], v1[2], v1[3]};
    *(f16x4*)&Vs[r][12] = (f16x4){v1[4], v1[5], v1[6], v1[7]};
#pragma unroll
    for (int d = 0; d < 8; ++d) { Vt[d][r] = v0[d]; Vt[d + 8][r] = v1[d]; }
  }

  const int lane = tid & 63, wave = tid >> 6;
  const int mi = lane & 15, quad = lane >> 4;

  int qtok[4];
  f16x4 qfr[4];
#pragma unroll
  for (int qi = 0; qi < 4; ++qi) {
    int q = (wave * 4 + qi) * 16 + mi;
    qtok[qi] = token_of(q);
    qfr[qi] = *(const f16x4*)(qh + base + q * 16 + quad * 4);
  }
  __syncthreads();

  f32x4 acc[4];
  float l[4];
#pragma unroll
  for (int qi = 0; qi < 4; ++qi) { acc[qi] = (f32x4){0.f,0.f,0.f,0.f}; l[qi] = 0.f; }

  const hf2 one2 = {(__fp16)1.f, (__fp16)1.f};

  for (int kt = 0; kt < 32; ++kt) {
    const int kb = kt << 4;
    f16x4 kfr = *(const f16x4*)&Ks[kb + mi][quad * 4];
    f16x4 vfr = *(const f16x4*)&Vt[mi][kb + quad * 4];
#pragma unroll
    for (int qi = 0; qi < 4; ++qi) {
      f32x4 s = __builtin_amdgcn_mfma_f32_16x16x16f16(kfr, qfr[qi], (f32x4){0.f,0.f,0.f,0.f}, 0, 0, 0);
      float p0 = EXP2F(s[0]);
      float p1 = EXP2F(s[1]);
      float p2 = EXP2F(s[2]);
      float p3 = EXP2F(s[3]);
      hf2 plo = __builtin_amdgcn_cvt_pkrtz(p0, p1);
      hf2 phi = __builtin_amdgcn_cvt_pkrtz(p2, p3);
#if __has_builtin(__builtin_amdgcn_fdot2)
      l[qi] = __builtin_amdgcn_fdot2(plo, one2, l[qi], false);
      l[qi] = __builtin_amdgcn_fdot2(phi, one2, l[qi], false);
#else
      l[qi] += (p0 + p1) + (p2 + p3);
#endif
      union { struct { hf2 lo, hi; } h; f16x4 v; } u;
      u.h.lo = plo; u.h.hi = phi;
      acc[qi] = __builtin_amdgcn_mfma_f32_16x16x16f16(vfr, u.v, acc[qi], 0, 0, 0);
    }
  }

#pragma unroll
  for (int qi = 0; qi < 4; ++qi) {
    float lq = l[qi];
    lq += __shfl_xor(lq, 16, 64);
    lq += __shfl_xor(lq, 32, 64);
    float inv = 1.f / lq;

    const int q = (wave * 4 + qi) * 16 + mi;
    int t_in = q >> 7, rem = q & 127;
    int h_in, w_in;
    if (br == 0) { h_in = rem >> 2; w_in = rem & 3; }
    else         { h_in = rem >> 5; w_in = rem & 31; }
    float4 lep = *(const float4*)(cb + head * 16 + quad * 4);
    for (int dz = 0; dz < 3; ++dz) {
      int tz = t_in + dz - 1; if ((unsigned)tz >= 4u) continue;
      for (int dy = 0; dy < 3; ++dy) {
        int ty = h_in + dy - 1; if ((unsigned)ty >= (unsigned)Hsp) continue;
        for (int dx = 0; dx < 3; ++dx) {
          int tx = w_in + dx - 1; if ((unsigned)tx >= (unsigned)Wsp) continue;
          int np = (tz * Hsp + ty) * Wsp + tx;
          int widx = (dz * 3 + dy) * 3 + dx;
          float4 w4 = *(const float4*)(lepw + ((br * 27 + widx) << 6) + head * 16 + quad * 4);
          f16x4 vv = *(const f16x4*)&Vs[np][quad * 4];
          lep.x += w4.x * (float)vv[0];
          lep.y += w4.y * (float)vv[1];
          lep.z += w4.z * (float)vv[2];
          lep.w += w4.w * (float)vv[3];
        }
      }
    }
    f16x4 ov;
    ov[0] = (_Float16)(acc[qi][0] * inv + lep.x);
    ov[1] = (_Float16)(acc[qi][1] * inv + lep.y);
    ov[2] = (_Float16)(acc[qi][2] * inv + lep.z);
    ov[3] = (_Float16)(acc[qi][3] * inv + lep.w);
    *(f16x4*)(attnh + (size_t)qtok[qi] * 128 + coff + quad * 4) = ov;
  }
}

// ---------------------------------------------------------------------------
// Kernel 3: FUSED proj + residual + LN2 + fc1 + GELU + fc2 + residual.
// 64 tokens/block, 512 threads (8 waves).  xr lives entirely in LDS (xrb);
// xrh never touches global memory.  Phase bodies are the R17/R18-passing
// k_proj / k_mlp code with xr redirected to LDS.
// LDS: as_ 17920 + wbuf 35840 + xrb 17920 = 71680 B -> 2 blocks/CU.
// ---------------------------------------------------------------------------
__global__ __launch_bounds__(512) void k_pm(
    const _Float16* __restrict__ attnh,
    const _Float16* __restrict__ pwh,
    const float* __restrict__ pb,
    const float* __restrict__ x,
    const float* __restrict__ nw,
    const float* __restrict__ nb,
    const _Float16* __restrict__ w1h,
    const float* __restrict__ f1b,
    const _Float16* __restrict__ w2h,
    const float* __restrict__ f2b,
    float* __restrict__ out)
{
  __shared__ _Float16 as_[64][LS];      // attnh stage -> later normalized x
  __shared__ _Float16 wbuf[128][LS];    // pw -> w1 -> w2; also reduce buffer
  __shared__ _Float16 xrb[64][LS];      // xr (proj + bias + residual), f16
  const int tid = threadIdx.x;
  const int row0 = blockIdx.x << 6;
  const int lane = tid & 63, wave = tid >> 6;
  const int mi = lane & 15, quad = lane >> 4;

  // ---- Phase A: proj -------------------------------------------------------
#pragma unroll
  for (int it = 0; it < 2; ++it) {
    int id = it * 512 + tid;             // 1024 units
    int r = id >> 4, c8 = id & 15;
    *(uint4*)&as_[r][c8 * 8] = *(const uint4*)(attnh + (size_t)(row0 + r) * 128 + c8 * 8);
  }
#pragma unroll
  for (int it = 0; it < 4; ++it) {
    int id = it * 512 + tid;             // 2048 units
    int r = id >> 4, c8 = id & 15;
    *(uint4*)&wbuf[r][c8 * 8] = *(const uint4*)(pwh + (size_t)r * 128 + c8 * 8);
  }
  __syncthreads();

  {
    const int mq = wave & 3, nh = wave >> 2;
    const int m0 = mq << 4;

    f16x8 afr[4];
#pragma unroll
    for (int kt = 0; kt < 4; ++kt)
      afr[kt] = *(const f16x8*)&as_[m0 + mi][kt * 32 + quad * 8];

    f32x4 acc[4];
#pragma unroll
    for (int nt = 0; nt < 4; ++nt) acc[nt] = (f32x4){0.f, 0.f, 0.f, 0.f};
#pragma unroll
    for (int nt = 0; nt < 4; ++nt) {
      int wrow = (nh * 4 + nt) * 16 + mi;
#pragma unroll
      for (int kt = 0; kt < 4; ++kt) {
        f16x8 bfr = *(const f16x8*)&wbuf[wrow][kt * 32 + quad * 8];
        acc[nt] = __builtin_amdgcn_mfma_f32_16x16x32_f16(afr[kt], bfr, acc[nt], 0, 0, 0);
      }
    }
    // C-layout write: xrb[token][n] = proj + bias
#pragma unroll
    for (int nt = 0; nt < 4; ++nt) {
      int n = (nh * 4 + nt) * 16 + mi;
      float bb = pb[n];
#pragma unroll
      for (int rr = 0; rr < 4; ++rr)
        xrb[m0 + quad * 4 + rr][n] = (_Float16)(acc[nt][rr] + bb);
    }
  }
  __syncthreads();

  // coalesced pass: xrb += x  (residual, fp32 global read)
#pragma unroll
  for (int it = 0; it < 2; ++it) {
    int id = it * 512 + tid;
    int r = id >> 4, c8 = id & 15;
    f16x8 v = *(const f16x8*)&xrb[r][c8 * 8];
    const float* xp = x + (size_t)(row0 + r) * 128 + c8 * 8;
    float4 xa = *(const float4*)xp;
    float4 xb = *(const float4*)(xp + 4);
    f16x8 o;
    o[0] = (_Float16)((float)v[0] + xa.x); o[1] = (_Float16)((float)v[1] + xa.y);
    o[2] = (_Float16)((float)v[2] + xa.z); o[3] = (_Float16)((float)v[3] + xa.w);
    o[4] = (_Float16)((float)v[4] + xb.x); o[5] = (_Float16)((float)v[5] + xb.y);
    o[6] = (_Float16)((float)v[6] + xb.z); o[7] = (_Float16)((float)v[7] + xb.w);
    *(f16x8*)&xrb[r][c8 * 8] = o;
  }
  __syncthreads();

  // ---- Phase B: LayerNorm2 (xrb -> as_) -----------------------------------
  {
    const int r = tid >> 3, j = tid & 7;
    float v[16];
#pragma unroll
    for (int i = 0; i < 2; ++i) {
      f16x8 u = *(const f16x8*)&xrb[r][j * 16 + i * 8];
#pragma unroll
      for (int k = 0; k < 8; ++k) v[i * 8 + k] = (float)u[k];
    }
    float s1 = 0.f, s2 = 0.f;
#pragma unroll
    for (int i = 0; i < 16; ++i) { s1 += v[i]; s2 += v[i] * v[i]; }
    s1 += __shfl_down(s1, 4, 8); s1 += __shfl_down(s1, 2, 8); s1 += __shfl_down(s1, 1, 8);
    s2 += __shfl_down(s2, 4, 8); s2 += __shfl_down(s2, 2, 8); s2 += __shfl_down(s2, 1, 8);
    float mu = __shfl(s1, 0, 8) * (1.f / 128.f);
    float ms = __shfl(s2, 0, 8) * (1.f / 128.f);
    float rstd = rsqrtf(ms - mu * mu + 1e-5f);
#pragma unroll
    for (int i = 0; i < 16; ++i) {
      int c = j * 16 + i;
      as_[r][c] = (_Float16)((v[i] - mu) * rstd * nw[c] + nb[c]);
    }
  }
  __syncthreads();

  // ---- Phase C: MLP (R18 k_mlp body; xs := as_, residual := xrb) ----------
  const int mt = wave & 3, hh = wave >> 2;
  const int tok0 = mt << 4;

  f16x8 bx[4];
#pragma unroll
  for (int kt = 0; kt < 4; ++kt)
    bx[kt] = *(const f16x8*)&as_[tok0 + mi][kt * 32 + quad * 8];

  f32x4 oacc[8];
#pragma unroll
  for (int o = 0; o < 8; ++o) oacc[o] = (f32x4){0.f, 0.f, 0.f, 0.f};

  auto gelu = [](float h) -> float {
    return h * __frcp_rn(1.f + EXP2F(-2.4554774f * h));
  };

  for (int ng = 0; ng < 4; ++ng) {
#pragma unroll
    for (int it = 0; it < 4; ++it) {
      int id = it * 512 + tid;
      int r = id >> 4, c8 = id & 15;
      *(uint4*)&wbuf[r][c8 * 8] = *(const uint4*)(w1h + (size_t)(ng * 128 + r) * 128 + c8 * 8);
    }
    __syncthreads();

    f32x4 hacc[4];
#pragma unroll
    for (int t = 0; t < 4; ++t) hacc[t] = (f32x4){0.f, 0.f, 0.f, 0.f};
#pragma unroll
    for (int t = 0; t < 4; ++t) {
      int hrow = hh * 64 + t * 16 + mi;
#pragma unroll
      for (int kt = 0; kt < 4; ++kt) {
        f16x8 wfr = *(const f16x8*)&wbuf[hrow][kt * 32 + quad * 8];
        hacc[t] = __builtin_amdgcn_mfma_f32_16x16x32_f16(wfr, bx[kt], hacc[t], 0, 0, 0);
      }
    }
    f16x4 ph[4];
#pragma unroll
    for (int t = 0; t < 4; ++t) {
      float4 bj = *(const float4*)(f1b + ng * 128 + hh * 64 + t * 16 + quad * 4);
      ph[t][0] = (_Float16)gelu(hacc[t][0] + bj.x);
      ph[t][1] = (_Float16)gelu(hacc[t][1] + bj.y);
      ph[t][2] = (_Float16)gelu(hacc[t][2] + bj.z);
      ph[t][3] = (_Float16)gelu(hacc[t][3] + bj.w);
    }
    __syncthreads();

#pragma unroll
    for (int it = 0; it < 4; ++it) {
      int id = it * 512 + tid;
      int r = id >> 4, c8 = id & 15;
      *(uint4*)&wbuf[r][c8 * 8] = *(const uint4*)(w2h + (size_t)r * 512 + ng * 128 + c8 * 8);
    }
    __syncthreads();

#pragma unroll
    for (int o = 0; o < 8; ++o) {
#pragma unroll
      for (int t = 0; t < 4; ++t) {
        f16x4 wfr = *(const f16x4*)&wbuf[o * 16 + mi][(hh * 4 + t) * 16 + quad * 4];
        oacc[o] = __builtin_amdgcn_mfma_f32_16x16x16f16(wfr, ph[t], oacc[o], 0, 0, 0);
      }
    }
    __syncthreads();
  }

  float* rbuf = (float*)wbuf;   // 32 * 256 * 4 = 32768 B <= 35840
  if (hh == 1) {
#pragma unroll
    for (int o = 0; o < 8; ++o)
#pragma unroll
      for (int k = 0; k < 4; ++k)
        rbuf[(o * 4 + k) * 256 + mt * 64 + lane] = oacc[o][k];
  }
  __syncthreads();
  if (hh == 0) {
#pragma unroll
    for (int o = 0; o < 8; ++o)
#pragma unroll
      for (int k = 0; k < 4; ++k)
        oacc[o][k] += rbuf[(o * 4 + k) * 256 + mt * 64 + lane];

#pragma unroll
    for (int o = 0; o < 8; ++o) {
      int row = row0 + tok0 + mi;
      int cb4 = o * 16 + quad * 4;
      float4 bo = *(const float4*)(f2b + cb4);
      f16x4 res = *(const f16x4*)&xrb[tok0 + mi][cb4];
      float4 ov;
      ov.x = oacc[o][0] + bo.x + (float)res[0];
      ov.y = oacc[o][1] + bo.y + (float)res[1];
      ov.z = oacc[o][2] + bo.z + (float)res[2];
      ov.w = oacc[o][3] + bo.w + (float)res[3];
      *(float4*)(out + (size_t)row * C_ + cb4) = ov;
    }
  }
}

// ---------------------------------------------------------------------------
extern "C" void kernel_launch(void* const* d_in, const int* in_sizes, int n_in,
                              void* d_out, int out_size, void* d_ws, size_t ws_size,
                              hipStream_t stream)
{
  const float* x    = (const float*)d_in[0];
  const float* n1w  = (const float*)d_in[1];
  const float* n1b  = (const float*)d_in[2];
  const float* qkvw = (const float*)d_in[3];
  const float* cw0  = (const float*)d_in[4];
  const float* cb0  = (const float*)d_in[5];
  const float* cw1  = (const float*)d_in[6];
  const float* cb1  = (const float*)d_in[7];
  const float* pw   = (const float*)d_in[8];
  const float* pb   = (const float*)d_in[9];
  const float* n2w  = (const float*)d_in[10];
  const float* n2b  = (const float*)d_in[11];
  const float* f1w  = (const float*)d_in[12];
  const float* f1b  = (const float*)d_in[13];
  const float* f2w  = (const float*)d_in[14];
  const float* f2b  = (const float*)d_in[15];

  char* ws = (char*)d_ws;
  _Float16* qh    = (_Float16*)ws;                    //  8388608 B
  _Float16* kh    = (_Float16*)(ws +  8388608);       //  8388608 B
  _Float16* vh    = (_Float16*)(ws + 16777216);       //  8388608 B
  _Float16* attnh = (_Float16*)(ws + 25165824);       //  8388608 B
  _Float16* wqh   = (_Float16*)(ws + 33554432);       //    98304 B
  _Float16* pwh   = (_Float16*)(ws + 33652736);       //    32768 B
  _Float16* w1h   = (_Float16*)(ws + 33685504);       //   131072 B
  _Float16* w2h   = (_Float16*)(ws + 33816576);       //   131072 B
  float*    lepw  = (float*)   (ws + 33947648);       //    13824 B

  k_cvt   <<<782,      256, 0, stream>>>(qkvw, pw, f1w, f2w, cw0, cw1,
                                         wqh, pwh, w1h, w2h, lepw);
  k_ln_qkv<<<BL / 64,  512, 0, stream>>>(x, n1w, n1b, wqh, qh, kh, vh);
  k_attn  <<<512,      512, 0, stream>>>(qh, kh, vh, lepw, cb0, cb1, attnh);
  k_pm    <<<BL / 64,  512, 0, stream>>>(attnh, pwh, pb, x, n2w, n2b,
                                         w1h, f1b, w2h, f2b, (float*)d_out);
}